// Round 10
// baseline (66.070 us; speedup 1.0000x reference)
//
#include <hip/hip_runtime.h>
#include <math.h>

#define EPSF     1.1920928955078125e-07f   // float32 eps
#define BYPASSF  0.9999998807907104f       // 1 - eps
#define CLAMPF   1e30f
#define NBATCH   32768

// split constants
#define INV2PI    0.15915494309189535f
#define INV2PI_HI 0.15915493667125701904f  // fp32(1/2pi)
#define INV2PI_LO 6.42063831e-9f           // 1/2pi - hi
#define L2E       1.4426950408889634f
#define L2E_HI    1.44269502162933349609f  // fp32(log2 e)
#define L2E_LO    1.92596299e-8f           // log2e - hi
#define LN2F      0.69314718055994530942f
#define PI_F      3.14159274101257324219f
#define PIO2_F    1.57079637050628662109f

// geometry: 16 subtrees/element, depth-6 local fold; paired: 2 elements/lane,
// block=1024 (64 element-pairs), grid=256
#define SLAB_SRC 504                       // floats per subtree slab in d_ws (63 steps * 8)
#define SLAB_LDS 508                       // floats per slab in LDS (2-way start-bank skew)
#define GDS_FLOATS (16 * SLAB_LDS + 120)   // + 15 top gates * 8 = 8248 floats = 32,992 B
#define LW_F4_STRIDE 65                    // leaf slab stride in float4
#define WS_NEED ((4096 + 8184) * 4)        // bytes: leaves + gates

typedef float v2 __attribute__((ext_vector_type(2)));

// inline function, NOT a macro: braced initializer lists in macro args split on commas
__device__ __forceinline__ v2 pkfma(v2 a, v2 b, v2 c) {
  return __builtin_elementwise_fma(a, b, c);
}

struct C2p { v2 r, i; };                   // one complex value for TWO batch elements

__device__ __attribute__((noinline)) float2 slow_sincos(float y) {
  return make_float2(sinf(y), cosf(y));
}

__device__ __forceinline__ void softmax3_store(float a, float b, float c, float* out) {
  float m = fmaxf(a, fmaxf(b, c));
  float e0 = expf(a - m), e1 = expf(b - m), e2 = expf(c - m);
  float s = (e0 + e1) + e2;
  out[0] = e0 / s; out[1] = e1 / s; out[2] = e2 / s;
}

__device__ __forceinline__ void softmax4(const float* __restrict__ in, float* out) {
  float a = in[0], b = in[1], c = in[2], d = in[3];
  float m = fmaxf(fmaxf(a, b), fmaxf(c, d));
  float e0 = expf(a - m), e1 = expf(b - m), e2 = expf(c - m), e3 = expf(d - m);
  float s = ((e0 + e1) + e2) + e3;
  out[0] = e0 / s; out[1] = e1 / s; out[2] = e2 / s; out[3] = e3 / s;
}

// bypass/eps folding (exact: probs sum to 1 -> at most one can exceed 1-eps)
__device__ __forceinline__ void fold_gate(float* p) {
  if (p[3] <= EPSF) p[3] = 0.0f;
  if (p[0] > BYPASSF)      { p[0]=1.f; p[1]=0.f; p[2]=0.f; p[3]=0.f; }
  else if (p[1] > BYPASSF) { p[0]=0.f; p[1]=1.f; p[2]=0.f; p[3]=0.f; }
  else if (p[2] > BYPASSF) { p[0]=0.f; p[1]=0.f; p[2]=1.f; p[3]=0.f; }
}

// ---------------- paired (2-element) combine primitives ----------------
// Per-element arithmetic is bit-identical to the R7 scalar path: packed ops
// perform the same fma/mul per half; trans ops run per component.
// NaN analysis: all inputs are clamped-finite; er,ei bounded by ~1e87 (xe<=200),
// lr/li finite-or--inf => dre/dim can be +inf but never NaN => fmed3 clamps
// are exactly nan_to_num(posinf=CLAMP)+clip.

__device__ __forceinline__ C2p combine2p(const float* __restrict__ g8, C2p L, C2p R,
                                         v2 x0, v2 x1) {
  float4 gl = *(const float4*)(g8);
  float4 gr = *(const float4*)(g8 + 4);
  v2 cL = pkfma((v2)(gl.z), x1, (v2)(gl.y) * x0) + (v2)(gl.x);
  v2 cR = pkfma((v2)(gr.z), x1, (v2)(gr.y) * x0) + (v2)(gr.x);
  v2 linr = pkfma((v2)(gl.w), L.r, cL);
  v2 lini = (v2)(gl.w) * L.i;
  v2 rinr = pkfma((v2)(gr.w), R.r, cR);
  v2 rini = (v2)(gr.w) * R.i;

  // sincos(lini) via revolution-domain Cody-Waite feeding HW v_sin/v_cos
  v2 sy, cy;
  {
    v2 t = lini * (v2)(INV2PI);
    v2 nf; nf.x = rintf(t.x); nf.y = rintf(t.y);
    v2 rv = pkfma(lini, (v2)(INV2PI_HI), -nf);
    rv     = pkfma(lini, (v2)(INV2PI_LO), rv);
    sy.x = __builtin_amdgcn_sinf(rv.x); sy.y = __builtin_amdgcn_sinf(rv.y);
    cy.x = __builtin_amdgcn_cosf(rv.x); cy.y = __builtin_amdgcn_cosf(rv.y);
    if (fabsf(lini.x) > 20000.0f) { float2 sc = slow_sincos(lini.x); sy.x = sc.x; cy.x = sc.y; }
    if (fabsf(lini.y) > 20000.0f) { float2 sc = slow_sincos(lini.y); sy.y = sc.x; cy.y = sc.y; }
  }

  // exp(linr) scaled: covers ldexp_cexpf region and over/underflow
  v2 xe; xe.x = __builtin_amdgcn_fmed3f(linr.x, -200.0f, 200.0f);
         xe.y = __builtin_amdgcn_fmed3f(linr.y, -200.0f, 200.0f);
  v2 t2 = xe * (v2)(L2E);
  v2 nfe; nfe.x = rintf(t2.x); nfe.y = rintf(t2.y);
  v2 f = pkfma(xe, (v2)(L2E_HI), -nfe);
  f     = pkfma(xe, (v2)(L2E_LO), f);
  v2 eh; eh.x = __builtin_amdgcn_exp2f(f.x); eh.y = __builtin_amdgcn_exp2f(f.y);
  int ne0 = (int)nfe.x, ne1 = (int)nfe.y;
  v2 ecr = eh * cy, eci = eh * sy;
  v2 er, ei;
  er.x = __builtin_amdgcn_ldexpf(ecr.x, ne0); er.y = __builtin_amdgcn_ldexpf(ecr.y, ne1);
  ei.x = __builtin_amdgcn_ldexpf(eci.x, ne0); ei.y = __builtin_amdgcn_ldexpf(eci.y, ne1);

  // clog: shared s = mn/mx for log-hypot and atan2
  v2 mx, mn;
  mx.x = fmaxf(fabsf(rinr.x), fabsf(rini.x)); mx.y = fmaxf(fabsf(rinr.y), fabsf(rini.y));
  mn.x = fminf(fabsf(rinr.x), fabsf(rini.x)); mn.y = fminf(fabsf(rinr.y), fabsf(rini.y));
  v2 rc; rc.x = __builtin_amdgcn_rcpf(mx.x); rc.y = __builtin_amdgcn_rcpf(mx.y);
  v2 s = mn * rc;
  s.x = (mx.x == 0.0f) ? 0.0f : s.x;
  s.y = (mx.y == 0.0f) ? 0.0f : s.y;
  v2 z = s * s;
  v2 lga; lga.x = __builtin_amdgcn_logf(z.x + 1.0f); lga.y = __builtin_amdgcn_logf(z.y + 1.0f);
  v2 lgm; lgm.x = __builtin_amdgcn_logf(mx.x);       lgm.y = __builtin_amdgcn_logf(mx.y);
  v2 lr = (v2)(LN2F) * pkfma((v2)(0.5f), lga, lgm);
  v2 u = (v2)(0.00282363896f);
  u = pkfma(u, z, (v2)(-0.0159569028f));
  u = pkfma(u, z, (v2)( 0.0425049886f));
  u = pkfma(u, z, (v2)(-0.0748900920f));
  u = pkfma(u, z, (v2)( 0.1063479334f));
  u = pkfma(u, z, (v2)(-0.1420273631f));
  u = pkfma(u, z, (v2)( 0.1999269574f));
  u = pkfma(u, z, (v2)(-0.3333310186f));
  v2 at = pkfma(s * z, u, s);
  v2 q1 = (v2)(PIO2_F) - at;
  at.x = (fabsf(rini.x) > fabsf(rinr.x)) ? q1.x : at.x;
  at.y = (fabsf(rini.y) > fabsf(rinr.y)) ? q1.y : at.y;
  v2 q2 = (v2)(PI_F) - at;
  at.x = (rinr.x < 0.0f) ? q2.x : at.x;
  at.y = (rinr.y < 0.0f) ? q2.y : at.y;
  v2 li; li.x = copysignf(at.x, rini.x); li.y = copysignf(at.y, rini.y);

  v2 dre = er - lr, dim = ei - li;
  C2p o;
  o.r.x = __builtin_amdgcn_fmed3f(dre.x, -CLAMPF, CLAMPF);
  o.r.y = __builtin_amdgcn_fmed3f(dre.y, -CLAMPF, CLAMPF);
  o.i.x = __builtin_amdgcn_fmed3f(dim.x, -CLAMPF, CLAMPF);
  o.i.y = __builtin_amdgcn_fmed3f(dim.y, -CLAMPF, CLAMPF);
  return o;
}

// level-1 specialization: both children are real leaves (imag exactly 0)
__device__ __forceinline__ C2p combine_l1p(const float* __restrict__ g8, v2 Lr, v2 Rr,
                                           v2 x0, v2 x1) {
  float4 gl = *(const float4*)(g8);
  float4 gr = *(const float4*)(g8 + 4);
  v2 lr_ = pkfma((v2)(gl.w), Lr, pkfma((v2)(gl.z), x1, (v2)(gl.y) * x0) + (v2)(gl.x));
  v2 rr_ = pkfma((v2)(gr.w), Rr, pkfma((v2)(gr.z), x1, (v2)(gr.y) * x0) + (v2)(gr.x));

  v2 xe; xe.x = __builtin_amdgcn_fmed3f(lr_.x, -200.0f, 200.0f);
         xe.y = __builtin_amdgcn_fmed3f(lr_.y, -200.0f, 200.0f);
  v2 t2 = xe * (v2)(L2E);
  v2 nfe; nfe.x = rintf(t2.x); nfe.y = rintf(t2.y);
  v2 f = pkfma(xe, (v2)(L2E_HI), -nfe);
  f     = pkfma(xe, (v2)(L2E_LO), f);
  v2 eh; eh.x = __builtin_amdgcn_exp2f(f.x); eh.y = __builtin_amdgcn_exp2f(f.y);
  v2 er;
  er.x = __builtin_amdgcn_ldexpf(eh.x, (int)nfe.x);
  er.y = __builtin_amdgcn_ldexpf(eh.y, (int)nfe.y);

  v2 lg; lg.x = __builtin_amdgcn_logf(fabsf(rr_.x)); lg.y = __builtin_amdgcn_logf(fabsf(rr_.y));
  v2 d = er - (v2)(LN2F) * lg;
  C2p o;
  o.r.x = __builtin_amdgcn_fmed3f(d.x, -CLAMPF, CLAMPF);  // NaN impossible on this path
  o.r.y = __builtin_amdgcn_fmed3f(d.y, -CLAMPF, CLAMPF);
  o.i.x = (rr_.x < 0.0f) ? -PI_F : 0.0f;
  o.i.y = (rr_.y < 0.0f) ? -PI_F : 0.0f;
  return o;
}

// quartet: 4 leaves -> depth-2 subtree root (3 combines at static offsets)
__device__ __forceinline__ C2p quartetp(const float* __restrict__ bp, const float4* __restrict__ lq,
                                        v2 x0, v2 x1) {
  float4 w0 = lq[0], w1 = lq[1], w2 = lq[2], w3 = lq[3];
  v2 a0 = pkfma((v2)(w0.z), x1, pkfma((v2)(w0.y), x0, (v2)(w0.x)));
  v2 a1 = pkfma((v2)(w1.z), x1, pkfma((v2)(w1.y), x0, (v2)(w1.x)));
  v2 a2 = pkfma((v2)(w2.z), x1, pkfma((v2)(w2.y), x0, (v2)(w2.x)));
  v2 a3 = pkfma((v2)(w3.z), x1, pkfma((v2)(w3.y), x0, (v2)(w3.x)));
  C2p c01 = combine_l1p(bp + 0, a0, a1, x0, x1);
  C2p c23 = combine_l1p(bp + 8, a2, a3, x0, x1);
  return combine2p(bp + 16, c01, c23, x0, x1);
}

// ---------------- prep: softmax + fold + DFS reorder into d_ws, plus probs outputs ----------------
__global__ __launch_bounds__(256) void prep_kernel(
    const float* __restrict__ leaf_logits,
    const float* __restrict__ gate_logits,
    float* __restrict__ out_leaf,   // 1024 x 3 raw
    float* __restrict__ out_gate,   // 2046 x 4 raw
    float* __restrict__ ws_leaf,    // 1024 float4 {w0,w1,w2,0}
    float* __restrict__ ws_gate) {  // 16*504 (DFS levels 1..6) + 15*8 (top)
  int i = blockIdx.x * 256 + threadIdx.x;
  if (i < 1024) {
    float p[3];
    softmax3_store(leaf_logits[i * 3], leaf_logits[i * 3 + 1], leaf_logits[i * 3 + 2], p);
    out_leaf[i * 3] = p[0]; out_leaf[i * 3 + 1] = p[1]; out_leaf[i * 3 + 2] = p[2];
    ((float4*)ws_leaf)[i] = make_float4(p[0], p[1], p[2], 0.0f);
  } else if (i < 1024 + 2046) {
    int j = i - 1024;                  // gate half-row 0..2045
    int g = j >> 1, half = j & 1;
    float p[4];
    softmax4(gate_logits + j * 4, p);
    ((float4*)out_gate)[j] = make_float4(p[0], p[1], p[2], p[3]);
    fold_gate(p);
    int di;
    if (g < 1008) {                    // levels 1..6 -> per-subtree DFS order
      int z  = 1024 - g;
      int k  = __clz(z - 1) - 21;      // 1..6
      int pp = g - (1024 - (2048 >> k));
      int t  = pp >> (6 - k);
      int pl = pp & ((1 << (6 - k)) - 1);
      int L  = ((pl + 1) << k) - 1;
      int step = L - __popc(L) + (k - 1);  // 0..62
      di = t * SLAB_SRC + step * 8;
    } else {
      di = 16 * SLAB_SRC + (g - 1008) * 8; // top 15 gates flat
    }
    ((float4*)(ws_gate + di))[half] = make_float4(p[0], p[1], p[2], p[3]);
  }
}

// ---------------- fast tree: 2 elements/lane, 16 lanes/pair, all-LDS operands ----------------
__global__ __launch_bounds__(1024, 1) void tree16p_kernel(
    const float* __restrict__ x,
    const float* __restrict__ ws_leaf,
    const float* __restrict__ ws_gate,
    float* __restrict__ out0, int cplx) {

  __shared__ __align__(16) float gds[GDS_FLOATS];             // 32,992 B
  __shared__ __align__(16) float lwds[16 * LW_F4_STRIDE * 4]; // 16,640 B
  const int tid = threadIdx.x;

  // copy gate table ws -> LDS, re-striding slabs 504 -> 508 (126 -> 127 float4)
  {
    float4* g4 = (float4*)gds;
    const float4* s4 = (const float4*)ws_gate;
    for (int c = tid; c < 2016; c += 1024) {
      int t = c / 126;
      int r = c - t * 126;
      g4[t * 127 + r] = s4[c];
    }
    if (tid < 30) g4[2032 + tid] = s4[2016 + tid];   // top gates
    // leaf table: float4 index l -> slab lt=l>>6, skewed stride 65
    float4* l4 = (float4*)lwds;
    const float4* sl = (const float4*)ws_leaf;
    l4[tid + (tid >> 6)] = sl[tid];
  }
  __syncthreads();

  const int gtid = blockIdx.x * 1024 + tid;
  const int pe = gtid >> 4;          // element pair (elements 2pe, 2pe+1)
  const int lt = tid & 15;           // subtree index
  const float4 xw = ((const float4*)x)[pe];
  v2 x0, x1;
  x0.x = xw.x; x0.y = xw.z;          // x[:,0] of both elements
  x1.x = xw.y; x1.y = xw.w;          // x[:,1] of both elements
  const float* gb  = &gds[lt * SLAB_LDS];
  const float* tds = &gds[16 * SLAB_LDS];
  const float4* lwp = (const float4*)lwds + lt * LW_F4_STRIDE;

  C2p p4, p5, p6;                    // pending left siblings, levels 4..6
  C2p res; res.r = (v2)(0.0f); res.i = (v2)(0.0f);
  int off = 0;                       // DFS step base * 8 floats

  // unroll 2: consecutive octets' quartets are independent -> ILP covers
  // trans-op latency at 4 waves/SIMD (VGPR headroom is 128/wave here)
  #pragma unroll 2
  for (int h2 = 0; h2 < 8; ++h2) {   // one octet (8 leaves, two quartets) per iteration
    const float* bp = gb + off;
    const float4* lq = lwp + 8 * h2;
    C2p c03 = quartetp(bp +  0, lq,     x0, x1);   // leaves 0..3, steps +0,+8,+16
    C2p c47 = quartetp(bp + 24, lq + 4, x0, x1);   // leaves 4..7, steps +24,+32,+40
    C2p cur = combine2p(bp + 48, c03, c47, x0, x1);
    // tail merges, levels 4..6 (DFS steps +56, +64, +72)
    if (!(h2 & 1)) { p4 = cur; }
    else {
      cur = combine2p(bp + 56, p4, cur, x0, x1);
      if (!(h2 & 2)) { p5 = cur; }
      else {
        cur = combine2p(bp + 64, p5, cur, x0, x1);
        if (!(h2 & 4)) { p6 = cur; }
        else           { res = combine2p(bp + 72, p6, cur, x0, x1); }
      }
    }
    off = (8 * (h2 + 1) - __popc(h2 + 1)) * 8;
  }

  // top 4 levels across the 16 lanes of this pair (gate rows 1008..1022 -> tds 0..14)
  C2p v = res;
  { C2p o;
    o.r.x = __shfl_xor(v.r.x, 1); o.r.y = __shfl_xor(v.r.y, 1);
    o.i.x = __shfl_xor(v.i.x, 1); o.i.y = __shfl_xor(v.i.y, 1);
    bool sw = (lt & 1);
    C2p L, R;
    L.r = sw ? o.r : v.r; L.i = sw ? o.i : v.i;
    R.r = sw ? v.r : o.r; R.i = sw ? v.i : o.i;
    v = combine2p(tds + (lt >> 1) * 8, L, R, x0, x1); }
  { C2p o;
    o.r.x = __shfl_xor(v.r.x, 2); o.r.y = __shfl_xor(v.r.y, 2);
    o.i.x = __shfl_xor(v.i.x, 2); o.i.y = __shfl_xor(v.i.y, 2);
    bool sw = (lt & 2);
    C2p L, R;
    L.r = sw ? o.r : v.r; L.i = sw ? o.i : v.i;
    R.r = sw ? v.r : o.r; R.i = sw ? v.i : o.i;
    v = combine2p(tds + (8 + (lt >> 2)) * 8, L, R, x0, x1); }
  { C2p o;
    o.r.x = __shfl_xor(v.r.x, 4); o.r.y = __shfl_xor(v.r.y, 4);
    o.i.x = __shfl_xor(v.i.x, 4); o.i.y = __shfl_xor(v.i.y, 4);
    bool sw = (lt & 4);
    C2p L, R;
    L.r = sw ? o.r : v.r; L.i = sw ? o.i : v.i;
    R.r = sw ? v.r : o.r; R.i = sw ? v.i : o.i;
    v = combine2p(tds + (12 + (lt >> 3)) * 8, L, R, x0, x1); }
  { C2p o;
    o.r.x = __shfl_xor(v.r.x, 8); o.r.y = __shfl_xor(v.r.y, 8);
    o.i.x = __shfl_xor(v.i.x, 8); o.i.y = __shfl_xor(v.i.y, 8);
    bool sw = (lt & 8);
    C2p L, R;
    L.r = sw ? o.r : v.r; L.i = sw ? o.i : v.i;
    R.r = sw ? v.r : o.r; R.i = sw ? v.i : o.i;
    v = combine2p(tds + 14 * 8, L, R, x0, x1); }

  if (lt == 0) {
    if (cplx) {
      ((float4*)out0)[pe] = make_float4(v.r.x, v.i.x, v.r.y, v.i.y);
    } else {
      ((float2*)out0)[pe] = make_float2(v.r.x, v.r.y);
    }
  }
}

// ---------------- fallback (R7 single-element path, used only if ws_size is too small) ----------------
#define GSTRIDE  1020
#define LSTRIDE  516

__device__ __forceinline__ v2 combine2(const float* __restrict__ g8, v2 L, v2 R,
                                       float x0, float x1) {
  float4 gl = *(const float4*)(g8);
  float4 gr = *(const float4*)(g8 + 4);
  float cL = fmaf(gl.z, x1, gl.y * x0) + gl.x;
  float cR = fmaf(gr.z, x1, gr.y * x0) + gr.x;
  v2 glw; glw.x = gl.w; glw.y = gl.w;
  v2 grw; grw.x = gr.w; grw.y = gr.w;
  v2 cLv; cLv.x = cL; cLv.y = 0.0f;
  v2 cRv; cRv.x = cR; cRv.y = 0.0f;
  v2 lin = pkfma(glw, L, cLv);
  v2 rin = pkfma(grw, R, cRv);
  float sy, cy;
  {
    float nf = rintf(lin.y * INV2PI);
    float rv = fmaf(lin.y, INV2PI_HI, -nf);
    rv       = fmaf(lin.y, INV2PI_LO, rv);
    sy = __builtin_amdgcn_sinf(rv);
    cy = __builtin_amdgcn_cosf(rv);
    if (fabsf(lin.y) > 20000.0f) { float2 sc = slow_sincos(lin.y); sy = sc.x; cy = sc.y; }
  }
  float xe = fminf(fmaxf(lin.x, -200.0f), 200.0f);
  float nfe = rintf(xe * L2E);
  float f  = fmaf(xe, L2E_HI, -nfe);
  f        = fmaf(xe, L2E_LO, f);
  float eh = __builtin_amdgcn_exp2f(f);
  int ne = (int)nfe;
  float er = __builtin_amdgcn_ldexpf(eh * cy, ne);
  float ei = __builtin_amdgcn_ldexpf(eh * sy, ne);
  float ax = fabsf(rin.x), ay = fabsf(rin.y);
  float mx = fmaxf(ax, ay), mn = fminf(ax, ay);
  float s  = (mx == 0.0f) ? 0.0f : mn * __builtin_amdgcn_rcpf(mx);
  float z  = s * s;
  float lr = LN2F * fmaf(0.5f, __builtin_amdgcn_logf(z + 1.0f), __builtin_amdgcn_logf(mx));
  float u =              0.00282363896f;
  u = fmaf(u, z, -0.0159569028f);
  u = fmaf(u, z,  0.0425049886f);
  u = fmaf(u, z, -0.0748900920f);
  u = fmaf(u, z,  0.1063479334f);
  u = fmaf(u, z, -0.1420273631f);
  u = fmaf(u, z,  0.1999269574f);
  u = fmaf(u, z, -0.3333310186f);
  float at = fmaf(s * z, u, s);
  at = (ay > ax)      ? (PIO2_F - at) : at;
  at = (rin.x < 0.0f) ? (PI_F   - at) : at;
  float li = copysignf(at, rin.y);
  float dx = er - lr, dy = ei - li;
  v2 o;
  o.x = (dx != dx) ? 0.0f : __builtin_amdgcn_fmed3f(dx, -CLAMPF, CLAMPF);
  o.y = (dy != dy) ? 0.0f : __builtin_amdgcn_fmed3f(dy, -CLAMPF, CLAMPF);
  return o;
}

__device__ __forceinline__ v2 combine_l1(const float* __restrict__ g8, float Lr, float Rr,
                                         float x0, float x1) {
  float4 gl = *(const float4*)(g8);
  float4 gr = *(const float4*)(g8 + 4);
  float lr_ = fmaf(gl.w, Lr, fmaf(gl.z, x1, gl.y * x0) + gl.x);
  float rr_ = fmaf(gr.w, Rr, fmaf(gr.z, x1, gr.y * x0) + gr.x);
  float xe = fminf(fmaxf(lr_, -200.0f), 200.0f);
  float nfe = rintf(xe * L2E);
  float f  = fmaf(xe, L2E_HI, -nfe);
  f        = fmaf(xe, L2E_LO, f);
  float eh = __builtin_amdgcn_exp2f(f);
  float er = __builtin_amdgcn_ldexpf(eh, (int)nfe);
  float lr = LN2F * __builtin_amdgcn_logf(fabsf(rr_));
  v2 o;
  o.x = fminf(fmaxf(er - lr, -CLAMPF), CLAMPF);
  o.y = (rr_ < 0.0f) ? -PI_F : 0.0f;
  return o;
}

__device__ __forceinline__ void store_gate_fb(const float* __restrict__ in, float* __restrict__ out) {
  float p[4];
  softmax4(in, p);
  fold_gate(p);
  out[0]=p[0]; out[1]=p[1]; out[2]=p[2]; out[3]=p[3];
}

__global__ __launch_bounds__(512) void tree_fb_kernel(
    const float* __restrict__ x,
    const float* __restrict__ leaf_logits,
    const float* __restrict__ gate_logits,
    float* __restrict__ out0, int cplx) {

  __shared__ __align__(16) float gds[8 * GSTRIDE];
  __shared__ __align__(16) float tds[7 * 8];
  __shared__ __align__(16) float lw[8 * LSTRIDE];
  const int tid = threadIdx.x;

  for (int l = tid; l < 1024; l += 512) {
    float p[3];
    softmax3_store(leaf_logits[l * 3], leaf_logits[l * 3 + 1], leaf_logits[l * 3 + 2], p);
    *(float4*)&lw[(l >> 7) * LSTRIDE + (l & 127) * 4] = make_float4(p[0], p[1], p[2], 0.0f);
  }
  for (int g = tid; g < 1016; g += 512) {
    int z  = 1024 - g;
    int k  = __clz(z - 1) - 21;
    int p  = g - (1024 - (2048 >> k));
    int t  = p >> (7 - k);
    int pl = p & ((1 << (7 - k)) - 1);
    int L  = ((pl + 1) << k) - 1;
    int step = L - __popc(L) + (k - 1);
    float* dst = &gds[t * GSTRIDE + step * 8];
    store_gate_fb(gate_logits + g * 8,     dst);
    store_gate_fb(gate_logits + g * 8 + 4, dst + 4);
  }
  if (tid < 7) {
    int g = 1016 + tid;
    store_gate_fb(gate_logits + g * 8,     &tds[tid * 8]);
    store_gate_fb(gate_logits + g * 8 + 4, &tds[tid * 8 + 4]);
  }
  __syncthreads();

  const int gtid = blockIdx.x * 512 + tid;
  const int e  = gtid >> 3;
  const int lt = tid & 7;
  const float2 xv = ((const float2*)x)[e];
  const float x0 = xv.x, x1 = xv.y;
  const float* gb = &gds[lt * GSTRIDE];
  const float* lb = &lw[lt * LSTRIDE];

  v2 p1, p2, p3, p4, p5, p6;
  v2 res = (v2)(0.0f);
  int step = 0;

  #pragma unroll 2
  for (int h = 0; h < 64; ++h) {
    float4 w0 = *(const float4*)&lb[(2 * h) * 4];
    float4 w1 = *(const float4*)&lb[(2 * h + 1) * 4];
    float a = fmaf(w0.z, x1, fmaf(w0.y, x0, w0.x));
    float b = fmaf(w1.z, x1, fmaf(w1.y, x0, w1.x));
    v2 cur = combine_l1(gb + step * 8, a, b, x0, x1); step++;
    if (!(h & 1))  { p1 = cur; continue; }
    cur = combine2(gb + step * 8, p1, cur, x0, x1); step++;
    if (!(h & 2))  { p2 = cur; continue; }
    cur = combine2(gb + step * 8, p2, cur, x0, x1); step++;
    if (!(h & 4))  { p3 = cur; continue; }
    cur = combine2(gb + step * 8, p3, cur, x0, x1); step++;
    if (!(h & 8))  { p4 = cur; continue; }
    cur = combine2(gb + step * 8, p4, cur, x0, x1); step++;
    if (!(h & 16)) { p5 = cur; continue; }
    cur = combine2(gb + step * 8, p5, cur, x0, x1); step++;
    if (!(h & 32)) { p6 = cur; continue; }
    cur = combine2(gb + step * 8, p6, cur, x0, x1); step++;
    res = cur;
  }

  v2 v = res;
  { v2 o; o.x = __shfl_xor(v.x, 1); o.y = __shfl_xor(v.y, 1);
    v2 L, R;
    L.x = (lt & 1) ? o.x : v.x; L.y = (lt & 1) ? o.y : v.y;
    R.x = (lt & 1) ? v.x : o.x; R.y = (lt & 1) ? v.y : o.y;
    v = combine2(&tds[(lt >> 1) * 8], L, R, x0, x1); }
  { v2 o; o.x = __shfl_xor(v.x, 2); o.y = __shfl_xor(v.y, 2);
    v2 L, R;
    L.x = (lt & 2) ? o.x : v.x; L.y = (lt & 2) ? o.y : v.y;
    R.x = (lt & 2) ? v.x : o.x; R.y = (lt & 2) ? v.y : o.y;
    v = combine2(&tds[(4 + (lt >> 2)) * 8], L, R, x0, x1); }
  { v2 o; o.x = __shfl_xor(v.x, 4); o.y = __shfl_xor(v.y, 4);
    v2 L, R;
    L.x = (lt & 4) ? o.x : v.x; L.y = (lt & 4) ? o.y : v.y;
    R.x = (lt & 4) ? v.x : o.x; R.y = (lt & 4) ? v.y : o.y;
    v = combine2(&tds[6 * 8], L, R, x0, x1); }

  if (lt == 0) {
    if (cplx) { out0[2 * e] = v.x; out0[2 * e + 1] = v.y; }
    else      { out0[e] = v.x; }
  }
}

__global__ __launch_bounds__(256) void probs_fb_kernel(
    const float* __restrict__ leaf_logits,
    const float* __restrict__ gate_logits,
    float* __restrict__ out_leaf,
    float* __restrict__ out_gate) {
  int i = blockIdx.x * 256 + threadIdx.x;
  if (i < 1024) {
    softmax3_store(leaf_logits[i * 3], leaf_logits[i * 3 + 1], leaf_logits[i * 3 + 2],
                   &out_leaf[i * 3]);
  } else if (i < 1024 + 2046) {
    int j = i - 1024;
    float p[4];
    softmax4(gate_logits + j * 4, p);
    ((float4*)out_gate)[j] = make_float4(p[0], p[1], p[2], p[3]);
  }
}

extern "C" void kernel_launch(void* const* d_in, const int* in_sizes, int n_in,
                              void* d_out, int out_size, void* d_ws, size_t ws_size,
                              hipStream_t stream) {
  const float* x  = (const float*)d_in[0];   // (32768, 2)
  const float* ll = (const float*)d_in[1];   // (1024, 3)
  const float* gl = (const float*)d_in[2];   // (1023, 2, 4)
  float* out0 = (float*)d_out;

  int S = out_size - (3072 + 8184);          // complex chunk: 2*32768 interleaved or 32768 real
  int cplx = (S >= 2 * NBATCH) ? 1 : 0;
  float* out_leaf = out0 + S;
  float* out_gate = out_leaf + 3072;

  if (ws_size >= (size_t)WS_NEED) {
    float* ws_leaf = (float*)d_ws;           // 4096 floats
    float* ws_gate = ws_leaf + 4096;         // 8184 floats
    prep_kernel<<<12, 256, 0, stream>>>(ll, gl, out_leaf, out_gate, ws_leaf, ws_gate);
    tree16p_kernel<<<256, 1024, 0, stream>>>(x, ws_leaf, ws_gate, out0, cplx);
  } else {
    tree_fb_kernel<<<512, 512, 0, stream>>>(x, ll, gl, out0, cplx);
    probs_fb_kernel<<<12, 256, 0, stream>>>(ll, gl, out_leaf, out_gate);
  }
}

// Round 11
// 54.933 us; speedup vs baseline: 1.2027x; 1.2027x over previous
//
#include <hip/hip_runtime.h>
#include <math.h>

#define EPSF     1.1920928955078125e-07f   // float32 eps
#define BYPASSF  0.9999998807907104f       // 1 - eps
#define CLAMPF   1e30f
#define NBATCH   32768

// split constants
#define INV2PI    0.15915494309189535f
#define INV2PI_HI 0.15915493667125701904f  // fp32(1/2pi)
#define INV2PI_LO 6.42063831e-9f           // 1/2pi - hi
#define L2E       1.4426950408889634f
#define L2E_HI    1.44269502162933349609f  // fp32(log2 e)
#define L2E_LO    1.92596299e-8f           // log2e - hi
#define LN2F      0.69314718055994530942f
#define PI_F      3.14159274101257324219f
#define PIO2_F    1.57079637050628662109f

// geometry: 32 subtrees/element (depth-5 local fold), 2 elements/lane,
// 32 lanes/pair, block=1024 (32 pairs), grid=512 -> 8 waves/SIMD, 2 blocks/CU
#define SLAB_SRC 248                       // floats per subtree slab in d_ws (31 steps * 8)
#define SLAB_LDS 252                       // floats per slab in LDS (16B-aligned, bank skew)
#define GDS_FLOATS (32 * SLAB_LDS + 248)   // + 31 top gates * 8 = 8312 floats = 33,248 B
#define LW_F4_STRIDE 33                    // leaf slab stride in float4 (32 + 1 skew)
#define WS_NEED ((4096 + 8184) * 4)        // bytes: leaves + gates

typedef float v2 __attribute__((ext_vector_type(2)));

// inline function, NOT a macro: braced initializer lists in macro args split on commas
__device__ __forceinline__ v2 pkfma(v2 a, v2 b, v2 c) {
  return __builtin_elementwise_fma(a, b, c);
}

struct C2p { v2 r, i; };                   // one complex value for TWO batch elements

__device__ __attribute__((noinline)) float2 slow_sincos(float y) {
  return make_float2(sinf(y), cosf(y));
}

__device__ __forceinline__ void softmax3_store(float a, float b, float c, float* out) {
  float m = fmaxf(a, fmaxf(b, c));
  float e0 = expf(a - m), e1 = expf(b - m), e2 = expf(c - m);
  float s = (e0 + e1) + e2;
  out[0] = e0 / s; out[1] = e1 / s; out[2] = e2 / s;
}

__device__ __forceinline__ void softmax4(const float* __restrict__ in, float* out) {
  float a = in[0], b = in[1], c = in[2], d = in[3];
  float m = fmaxf(fmaxf(a, b), fmaxf(c, d));
  float e0 = expf(a - m), e1 = expf(b - m), e2 = expf(c - m), e3 = expf(d - m);
  float s = ((e0 + e1) + e2) + e3;
  out[0] = e0 / s; out[1] = e1 / s; out[2] = e2 / s; out[3] = e3 / s;
}

// bypass/eps folding (exact: probs sum to 1 -> at most one can exceed 1-eps)
__device__ __forceinline__ void fold_gate(float* p) {
  if (p[3] <= EPSF) p[3] = 0.0f;
  if (p[0] > BYPASSF)      { p[0]=1.f; p[1]=0.f; p[2]=0.f; p[3]=0.f; }
  else if (p[1] > BYPASSF) { p[0]=0.f; p[1]=1.f; p[2]=0.f; p[3]=0.f; }
  else if (p[2] > BYPASSF) { p[0]=0.f; p[1]=0.f; p[2]=1.f; p[3]=0.f; }
}

// ---------------- paired (2-element) combine primitives ----------------
// Per-element arithmetic is bit-identical to the R7 scalar path.
// NaN analysis: inputs clamped-finite; er,ei bounded ~1e87 (xe<=200); lr/li
// finite-or--inf => dre/dim can be +inf but never NaN => fmed3 clamp is
// exactly nan_to_num(posinf=CLAMP)+clip.

__device__ __forceinline__ C2p combine2p(const float* __restrict__ g8, C2p L, C2p R,
                                         v2 x0, v2 x1) {
  float4 gl = *(const float4*)(g8);
  float4 gr = *(const float4*)(g8 + 4);
  v2 cL = pkfma((v2)(gl.z), x1, (v2)(gl.y) * x0) + (v2)(gl.x);
  v2 cR = pkfma((v2)(gr.z), x1, (v2)(gr.y) * x0) + (v2)(gr.x);
  v2 linr = pkfma((v2)(gl.w), L.r, cL);
  v2 lini = (v2)(gl.w) * L.i;
  v2 rinr = pkfma((v2)(gr.w), R.r, cR);
  v2 rini = (v2)(gr.w) * R.i;

  // sincos(lini) via revolution-domain Cody-Waite feeding HW v_sin/v_cos
  v2 sy, cy;
  {
    v2 t = lini * (v2)(INV2PI);
    v2 nf; nf.x = rintf(t.x); nf.y = rintf(t.y);
    v2 rv = pkfma(lini, (v2)(INV2PI_HI), -nf);
    rv     = pkfma(lini, (v2)(INV2PI_LO), rv);
    sy.x = __builtin_amdgcn_sinf(rv.x); sy.y = __builtin_amdgcn_sinf(rv.y);
    cy.x = __builtin_amdgcn_cosf(rv.x); cy.y = __builtin_amdgcn_cosf(rv.y);
    if (fabsf(lini.x) > 20000.0f) { float2 sc = slow_sincos(lini.x); sy.x = sc.x; cy.x = sc.y; }
    if (fabsf(lini.y) > 20000.0f) { float2 sc = slow_sincos(lini.y); sy.y = sc.x; cy.y = sc.y; }
  }

  // exp(linr) scaled: covers ldexp_cexpf region and over/underflow
  v2 xe; xe.x = __builtin_amdgcn_fmed3f(linr.x, -200.0f, 200.0f);
         xe.y = __builtin_amdgcn_fmed3f(linr.y, -200.0f, 200.0f);
  v2 t2 = xe * (v2)(L2E);
  v2 nfe; nfe.x = rintf(t2.x); nfe.y = rintf(t2.y);
  v2 f = pkfma(xe, (v2)(L2E_HI), -nfe);
  f     = pkfma(xe, (v2)(L2E_LO), f);
  v2 eh; eh.x = __builtin_amdgcn_exp2f(f.x); eh.y = __builtin_amdgcn_exp2f(f.y);
  int ne0 = (int)nfe.x, ne1 = (int)nfe.y;
  v2 ecr = eh * cy, eci = eh * sy;
  v2 er, ei;
  er.x = __builtin_amdgcn_ldexpf(ecr.x, ne0); er.y = __builtin_amdgcn_ldexpf(ecr.y, ne1);
  ei.x = __builtin_amdgcn_ldexpf(eci.x, ne0); ei.y = __builtin_amdgcn_ldexpf(eci.y, ne1);

  // clog: shared s = mn/mx for log-hypot and atan2
  v2 mx, mn;
  mx.x = fmaxf(fabsf(rinr.x), fabsf(rini.x)); mx.y = fmaxf(fabsf(rinr.y), fabsf(rini.y));
  mn.x = fminf(fabsf(rinr.x), fabsf(rini.x)); mn.y = fminf(fabsf(rinr.y), fabsf(rini.y));
  v2 rc; rc.x = __builtin_amdgcn_rcpf(mx.x); rc.y = __builtin_amdgcn_rcpf(mx.y);
  v2 s = mn * rc;
  s.x = (mx.x == 0.0f) ? 0.0f : s.x;
  s.y = (mx.y == 0.0f) ? 0.0f : s.y;
  v2 z = s * s;
  v2 lga; lga.x = __builtin_amdgcn_logf(z.x + 1.0f); lga.y = __builtin_amdgcn_logf(z.y + 1.0f);
  v2 lgm; lgm.x = __builtin_amdgcn_logf(mx.x);       lgm.y = __builtin_amdgcn_logf(mx.y);
  v2 lr = (v2)(LN2F) * pkfma((v2)(0.5f), lga, lgm);
  v2 u = (v2)(0.00282363896f);
  u = pkfma(u, z, (v2)(-0.0159569028f));
  u = pkfma(u, z, (v2)( 0.0425049886f));
  u = pkfma(u, z, (v2)(-0.0748900920f));
  u = pkfma(u, z, (v2)( 0.1063479334f));
  u = pkfma(u, z, (v2)(-0.1420273631f));
  u = pkfma(u, z, (v2)( 0.1999269574f));
  u = pkfma(u, z, (v2)(-0.3333310186f));
  v2 at = pkfma(s * z, u, s);
  v2 q1 = (v2)(PIO2_F) - at;
  at.x = (fabsf(rini.x) > fabsf(rinr.x)) ? q1.x : at.x;
  at.y = (fabsf(rini.y) > fabsf(rinr.y)) ? q1.y : at.y;
  v2 q2 = (v2)(PI_F) - at;
  at.x = (rinr.x < 0.0f) ? q2.x : at.x;
  at.y = (rinr.y < 0.0f) ? q2.y : at.y;
  v2 li; li.x = copysignf(at.x, rini.x); li.y = copysignf(at.y, rini.y);

  v2 dre = er - lr, dim = ei - li;
  C2p o;
  o.r.x = __builtin_amdgcn_fmed3f(dre.x, -CLAMPF, CLAMPF);
  o.r.y = __builtin_amdgcn_fmed3f(dre.y, -CLAMPF, CLAMPF);
  o.i.x = __builtin_amdgcn_fmed3f(dim.x, -CLAMPF, CLAMPF);
  o.i.y = __builtin_amdgcn_fmed3f(dim.y, -CLAMPF, CLAMPF);
  return o;
}

// level-1 specialization: both children are real leaves (imag exactly 0)
__device__ __forceinline__ C2p combine_l1p(const float* __restrict__ g8, v2 Lr, v2 Rr,
                                           v2 x0, v2 x1) {
  float4 gl = *(const float4*)(g8);
  float4 gr = *(const float4*)(g8 + 4);
  v2 lr_ = pkfma((v2)(gl.w), Lr, pkfma((v2)(gl.z), x1, (v2)(gl.y) * x0) + (v2)(gl.x));
  v2 rr_ = pkfma((v2)(gr.w), Rr, pkfma((v2)(gr.z), x1, (v2)(gr.y) * x0) + (v2)(gr.x));

  v2 xe; xe.x = __builtin_amdgcn_fmed3f(lr_.x, -200.0f, 200.0f);
         xe.y = __builtin_amdgcn_fmed3f(lr_.y, -200.0f, 200.0f);
  v2 t2 = xe * (v2)(L2E);
  v2 nfe; nfe.x = rintf(t2.x); nfe.y = rintf(t2.y);
  v2 f = pkfma(xe, (v2)(L2E_HI), -nfe);
  f     = pkfma(xe, (v2)(L2E_LO), f);
  v2 eh; eh.x = __builtin_amdgcn_exp2f(f.x); eh.y = __builtin_amdgcn_exp2f(f.y);
  v2 er;
  er.x = __builtin_amdgcn_ldexpf(eh.x, (int)nfe.x);
  er.y = __builtin_amdgcn_ldexpf(eh.y, (int)nfe.y);

  v2 lg; lg.x = __builtin_amdgcn_logf(fabsf(rr_.x)); lg.y = __builtin_amdgcn_logf(fabsf(rr_.y));
  v2 d = er - (v2)(LN2F) * lg;
  C2p o;
  o.r.x = __builtin_amdgcn_fmed3f(d.x, -CLAMPF, CLAMPF);  // NaN impossible on this path
  o.r.y = __builtin_amdgcn_fmed3f(d.y, -CLAMPF, CLAMPF);
  o.i.x = (rr_.x < 0.0f) ? -PI_F : 0.0f;
  o.i.y = (rr_.y < 0.0f) ? -PI_F : 0.0f;
  return o;
}

// quartet: 4 leaves -> depth-2 subtree root (3 combines at static offsets)
__device__ __forceinline__ C2p quartetp(const float* __restrict__ bp, const float4* __restrict__ lq,
                                        v2 x0, v2 x1) {
  float4 w0 = lq[0], w1 = lq[1], w2 = lq[2], w3 = lq[3];
  v2 a0 = pkfma((v2)(w0.z), x1, pkfma((v2)(w0.y), x0, (v2)(w0.x)));
  v2 a1 = pkfma((v2)(w1.z), x1, pkfma((v2)(w1.y), x0, (v2)(w1.x)));
  v2 a2 = pkfma((v2)(w2.z), x1, pkfma((v2)(w2.y), x0, (v2)(w2.x)));
  v2 a3 = pkfma((v2)(w3.z), x1, pkfma((v2)(w3.y), x0, (v2)(w3.x)));
  C2p c01 = combine_l1p(bp + 0, a0, a1, x0, x1);
  C2p c23 = combine_l1p(bp + 8, a2, a3, x0, x1);
  return combine2p(bp + 16, c01, c23, x0, x1);
}

// ---------------- prep: softmax + fold + DFS reorder into d_ws, plus probs outputs ----------------
__global__ __launch_bounds__(256) void prep_kernel(
    const float* __restrict__ leaf_logits,
    const float* __restrict__ gate_logits,
    float* __restrict__ out_leaf,   // 1024 x 3 raw
    float* __restrict__ out_gate,   // 2046 x 4 raw
    float* __restrict__ ws_leaf,    // 1024 float4 {w0,w1,w2,0}
    float* __restrict__ ws_gate) {  // 32*248 (DFS levels 1..5) + 31*8 (top, rows 992..1022)
  int i = blockIdx.x * 256 + threadIdx.x;
  if (i < 1024) {
    float p[3];
    softmax3_store(leaf_logits[i * 3], leaf_logits[i * 3 + 1], leaf_logits[i * 3 + 2], p);
    out_leaf[i * 3] = p[0]; out_leaf[i * 3 + 1] = p[1]; out_leaf[i * 3 + 2] = p[2];
    ((float4*)ws_leaf)[i] = make_float4(p[0], p[1], p[2], 0.0f);
  } else if (i < 1024 + 2046) {
    int j = i - 1024;                  // gate half-row 0..2045
    int g = j >> 1, half = j & 1;
    float p[4];
    softmax4(gate_logits + j * 4, p);
    ((float4*)out_gate)[j] = make_float4(p[0], p[1], p[2], p[3]);
    fold_gate(p);
    int di;
    if (g < 992) {                     // levels 1..5 -> per-subtree DFS order
      int z  = 1024 - g;
      int k  = __clz(z - 1) - 21;      // 1..5
      int pp = g - (1024 - (2048 >> k));
      int t  = pp >> (5 - k);
      int pl = pp & ((1 << (5 - k)) - 1);
      int L  = ((pl + 1) << k) - 1;
      int step = L - __popc(L) + (k - 1);  // 0..30
      di = t * SLAB_SRC + step * 8;
    } else {
      di = 32 * SLAB_SRC + (g - 992) * 8;  // top 31 gates flat
    }
    ((float4*)(ws_gate + di))[half] = make_float4(p[0], p[1], p[2], p[3]);
  }
}

// ---------------- fast tree: 2 elems/lane, 32 lanes/pair, depth-5 subtrees, all-LDS ----------------
__global__ __launch_bounds__(1024, 2) void tree32p_kernel(
    const float* __restrict__ x,
    const float* __restrict__ ws_leaf,
    const float* __restrict__ ws_gate,
    float* __restrict__ out0, int cplx) {

  __shared__ __align__(16) float gds[GDS_FLOATS];             // 33,248 B
  __shared__ __align__(16) float lwds[32 * LW_F4_STRIDE * 4]; // 16,896 B
  const int tid = threadIdx.x;

  // copy gate table ws -> LDS, re-striding slabs 248 -> 252 floats (62 -> 63 float4)
  {
    float4* g4 = (float4*)gds;
    const float4* s4 = (const float4*)ws_gate;
    for (int c = tid; c < 1984; c += 1024) {
      int t = c / 62;
      int r = c - t * 62;
      g4[t * 63 + r] = s4[c];
    }
    if (tid < 62) g4[2016 + tid] = s4[1984 + tid];   // top gates (31 x 2 float4)
    // leaf table: float4 index l -> slab lt=l>>5, skewed stride 33
    float4* l4 = (float4*)lwds;
    const float4* sl = (const float4*)ws_leaf;
    l4[tid + (tid >> 5)] = sl[tid];
  }
  __syncthreads();

  const int gtid = blockIdx.x * 1024 + tid;
  const int pe = gtid >> 5;          // element pair (elements 2pe, 2pe+1)
  const int lt = tid & 31;           // subtree index
  const float4 xw = ((const float4*)x)[pe];
  v2 x0, x1;
  x0.x = xw.x; x0.y = xw.z;          // x[:,0] of both elements
  x1.x = xw.y; x1.y = xw.w;          // x[:,1] of both elements
  const float* gb  = &gds[lt * SLAB_LDS];
  const float* tds = &gds[32 * SLAB_LDS];
  const float4* lwp = (const float4*)lwds + lt * LW_F4_STRIDE;

  C2p p4, p5;                        // pending left siblings, levels 4..5
  C2p res; res.r = (v2)(0.0f); res.i = (v2)(0.0f);
  int off = 0;                       // DFS step base * 8 floats

  #pragma unroll 1
  for (int h2 = 0; h2 < 4; ++h2) {   // one octet (8 leaves, two quartets) per iteration
    const float* bp = gb + off;
    const float4* lq = lwp + 8 * h2;
    C2p c03 = quartetp(bp +  0, lq,     x0, x1);   // leaves 0..3, steps +0,+8,+16
    C2p c47 = quartetp(bp + 24, lq + 4, x0, x1);   // leaves 4..7, steps +24,+32,+40
    C2p cur = combine2p(bp + 48, c03, c47, x0, x1);
    // tail merges, levels 4..5 (DFS steps +56, +64)
    if (!(h2 & 1)) { p4 = cur; }
    else {
      cur = combine2p(bp + 56, p4, cur, x0, x1);
      if (!(h2 & 2)) { p5 = cur; }
      else           { res = combine2p(bp + 64, p5, cur, x0, x1); }
    }
    off = (8 * (h2 + 1) - __popc(h2 + 1)) * 8;
  }

  // top 5 levels across the 32 lanes of this pair (gate rows 992..1022 -> tds 0..30)
  C2p v = res;
  { C2p o;
    o.r.x = __shfl_xor(v.r.x, 1); o.r.y = __shfl_xor(v.r.y, 1);
    o.i.x = __shfl_xor(v.i.x, 1); o.i.y = __shfl_xor(v.i.y, 1);
    bool sw = (lt & 1);
    C2p L, R;
    L.r = sw ? o.r : v.r; L.i = sw ? o.i : v.i;
    R.r = sw ? v.r : o.r; R.i = sw ? v.i : o.i;
    v = combine2p(tds + (lt >> 1) * 8, L, R, x0, x1); }          // level 6: rows 992+
  { C2p o;
    o.r.x = __shfl_xor(v.r.x, 2); o.r.y = __shfl_xor(v.r.y, 2);
    o.i.x = __shfl_xor(v.i.x, 2); o.i.y = __shfl_xor(v.i.y, 2);
    bool sw = (lt & 2);
    C2p L, R;
    L.r = sw ? o.r : v.r; L.i = sw ? o.i : v.i;
    R.r = sw ? v.r : o.r; R.i = sw ? v.i : o.i;
    v = combine2p(tds + (16 + (lt >> 2)) * 8, L, R, x0, x1); }   // level 7: rows 1008+
  { C2p o;
    o.r.x = __shfl_xor(v.r.x, 4); o.r.y = __shfl_xor(v.r.y, 4);
    o.i.x = __shfl_xor(v.i.x, 4); o.i.y = __shfl_xor(v.i.y, 4);
    bool sw = (lt & 4);
    C2p L, R;
    L.r = sw ? o.r : v.r; L.i = sw ? o.i : v.i;
    R.r = sw ? v.r : o.r; R.i = sw ? v.i : o.i;
    v = combine2p(tds + (24 + (lt >> 3)) * 8, L, R, x0, x1); }   // level 8: rows 1016+
  { C2p o;
    o.r.x = __shfl_xor(v.r.x, 8); o.r.y = __shfl_xor(v.r.y, 8);
    o.i.x = __shfl_xor(v.i.x, 8); o.i.y = __shfl_xor(v.i.y, 8);
    bool sw = (lt & 8);
    C2p L, R;
    L.r = sw ? o.r : v.r; L.i = sw ? o.i : v.i;
    R.r = sw ? v.r : o.r; R.i = sw ? v.i : o.i;
    v = combine2p(tds + (28 + (lt >> 4)) * 8, L, R, x0, x1); }   // level 9: rows 1020+
  { C2p o;
    o.r.x = __shfl_xor(v.r.x, 16); o.r.y = __shfl_xor(v.r.y, 16);
    o.i.x = __shfl_xor(v.i.x, 16); o.i.y = __shfl_xor(v.i.y, 16);
    bool sw = (lt & 16);
    C2p L, R;
    L.r = sw ? o.r : v.r; L.i = sw ? o.i : v.i;
    R.r = sw ? v.r : o.r; R.i = sw ? v.i : o.i;
    v = combine2p(tds + 30 * 8, L, R, x0, x1); }                 // level 10 root: row 1022

  if (lt == 0) {
    if (cplx) {
      ((float4*)out0)[pe] = make_float4(v.r.x, v.i.x, v.r.y, v.i.y);
    } else {
      ((float2*)out0)[pe] = make_float2(v.r.x, v.r.y);
    }
  }
}

// ---------------- fallback (single-element path, used only if ws_size is too small) ----------------
#define GSTRIDE  1020
#define LSTRIDE  516

__device__ __forceinline__ v2 combine2(const float* __restrict__ g8, v2 L, v2 R,
                                       float x0, float x1) {
  float4 gl = *(const float4*)(g8);
  float4 gr = *(const float4*)(g8 + 4);
  float cL = fmaf(gl.z, x1, gl.y * x0) + gl.x;
  float cR = fmaf(gr.z, x1, gr.y * x0) + gr.x;
  v2 glw; glw.x = gl.w; glw.y = gl.w;
  v2 grw; grw.x = gr.w; grw.y = gr.w;
  v2 cLv; cLv.x = cL; cLv.y = 0.0f;
  v2 cRv; cRv.x = cR; cRv.y = 0.0f;
  v2 lin = pkfma(glw, L, cLv);
  v2 rin = pkfma(grw, R, cRv);
  float sy, cy;
  {
    float nf = rintf(lin.y * INV2PI);
    float rv = fmaf(lin.y, INV2PI_HI, -nf);
    rv       = fmaf(lin.y, INV2PI_LO, rv);
    sy = __builtin_amdgcn_sinf(rv);
    cy = __builtin_amdgcn_cosf(rv);
    if (fabsf(lin.y) > 20000.0f) { float2 sc = slow_sincos(lin.y); sy = sc.x; cy = sc.y; }
  }
  float xe = fminf(fmaxf(lin.x, -200.0f), 200.0f);
  float nfe = rintf(xe * L2E);
  float f  = fmaf(xe, L2E_HI, -nfe);
  f        = fmaf(xe, L2E_LO, f);
  float eh = __builtin_amdgcn_exp2f(f);
  int ne = (int)nfe;
  float er = __builtin_amdgcn_ldexpf(eh * cy, ne);
  float ei = __builtin_amdgcn_ldexpf(eh * sy, ne);
  float ax = fabsf(rin.x), ay = fabsf(rin.y);
  float mx = fmaxf(ax, ay), mn = fminf(ax, ay);
  float s  = (mx == 0.0f) ? 0.0f : mn * __builtin_amdgcn_rcpf(mx);
  float z  = s * s;
  float lr = LN2F * fmaf(0.5f, __builtin_amdgcn_logf(z + 1.0f), __builtin_amdgcn_logf(mx));
  float u =              0.00282363896f;
  u = fmaf(u, z, -0.0159569028f);
  u = fmaf(u, z,  0.0425049886f);
  u = fmaf(u, z, -0.0748900920f);
  u = fmaf(u, z,  0.1063479334f);
  u = fmaf(u, z, -0.1420273631f);
  u = fmaf(u, z,  0.1999269574f);
  u = fmaf(u, z, -0.3333310186f);
  float at = fmaf(s * z, u, s);
  at = (ay > ax)      ? (PIO2_F - at) : at;
  at = (rin.x < 0.0f) ? (PI_F   - at) : at;
  float li = copysignf(at, rin.y);
  float dx = er - lr, dy = ei - li;
  v2 o;
  o.x = (dx != dx) ? 0.0f : __builtin_amdgcn_fmed3f(dx, -CLAMPF, CLAMPF);
  o.y = (dy != dy) ? 0.0f : __builtin_amdgcn_fmed3f(dy, -CLAMPF, CLAMPF);
  return o;
}

__device__ __forceinline__ v2 combine_l1(const float* __restrict__ g8, float Lr, float Rr,
                                         float x0, float x1) {
  float4 gl = *(const float4*)(g8);
  float4 gr = *(const float4*)(g8 + 4);
  float lr_ = fmaf(gl.w, Lr, fmaf(gl.z, x1, gl.y * x0) + gl.x);
  float rr_ = fmaf(gr.w, Rr, fmaf(gr.z, x1, gr.y * x0) + gr.x);
  float xe = fminf(fmaxf(lr_, -200.0f), 200.0f);
  float nfe = rintf(xe * L2E);
  float f  = fmaf(xe, L2E_HI, -nfe);
  f        = fmaf(xe, L2E_LO, f);
  float eh = __builtin_amdgcn_exp2f(f);
  float er = __builtin_amdgcn_ldexpf(eh, (int)nfe);
  float lr = LN2F * __builtin_amdgcn_logf(fabsf(rr_));
  v2 o;
  o.x = fminf(fmaxf(er - lr, -CLAMPF), CLAMPF);
  o.y = (rr_ < 0.0f) ? -PI_F : 0.0f;
  return o;
}

__device__ __forceinline__ void store_gate_fb(const float* __restrict__ in, float* __restrict__ out) {
  float p[4];
  softmax4(in, p);
  fold_gate(p);
  out[0]=p[0]; out[1]=p[1]; out[2]=p[2]; out[3]=p[3];
}

__global__ __launch_bounds__(512) void tree_fb_kernel(
    const float* __restrict__ x,
    const float* __restrict__ leaf_logits,
    const float* __restrict__ gate_logits,
    float* __restrict__ out0, int cplx) {

  __shared__ __align__(16) float gds[8 * GSTRIDE];
  __shared__ __align__(16) float tds[7 * 8];
  __shared__ __align__(16) float lw[8 * LSTRIDE];
  const int tid = threadIdx.x;

  for (int l = tid; l < 1024; l += 512) {
    float p[3];
    softmax3_store(leaf_logits[l * 3], leaf_logits[l * 3 + 1], leaf_logits[l * 3 + 2], p);
    *(float4*)&lw[(l >> 7) * LSTRIDE + (l & 127) * 4] = make_float4(p[0], p[1], p[2], 0.0f);
  }
  for (int g = tid; g < 1016; g += 512) {
    int z  = 1024 - g;
    int k  = __clz(z - 1) - 21;
    int p  = g - (1024 - (2048 >> k));
    int t  = p >> (7 - k);
    int pl = p & ((1 << (7 - k)) - 1);
    int L  = ((pl + 1) << k) - 1;
    int step = L - __popc(L) + (k - 1);
    float* dst = &gds[t * GSTRIDE + step * 8];
    store_gate_fb(gate_logits + g * 8,     dst);
    store_gate_fb(gate_logits + g * 8 + 4, dst + 4);
  }
  if (tid < 7) {
    int g = 1016 + tid;
    store_gate_fb(gate_logits + g * 8,     &tds[tid * 8]);
    store_gate_fb(gate_logits + g * 8 + 4, &tds[tid * 8 + 4]);
  }
  __syncthreads();

  const int gtid = blockIdx.x * 512 + tid;
  const int e  = gtid >> 3;
  const int lt = tid & 7;
  const float2 xv = ((const float2*)x)[e];
  const float x0 = xv.x, x1 = xv.y;
  const float* gb = &gds[lt * GSTRIDE];
  const float* lb = &lw[lt * LSTRIDE];

  v2 p1, p2, p3, p4, p5, p6;
  v2 res = (v2)(0.0f);
  int step = 0;

  #pragma unroll 2
  for (int h = 0; h < 64; ++h) {
    float4 w0 = *(const float4*)&lb[(2 * h) * 4];
    float4 w1 = *(const float4*)&lb[(2 * h + 1) * 4];
    float a = fmaf(w0.z, x1, fmaf(w0.y, x0, w0.x));
    float b = fmaf(w1.z, x1, fmaf(w1.y, x0, w1.x));
    v2 cur = combine_l1(gb + step * 8, a, b, x0, x1); step++;
    if (!(h & 1))  { p1 = cur; continue; }
    cur = combine2(gb + step * 8, p1, cur, x0, x1); step++;
    if (!(h & 2))  { p2 = cur; continue; }
    cur = combine2(gb + step * 8, p2, cur, x0, x1); step++;
    if (!(h & 4))  { p3 = cur; continue; }
    cur = combine2(gb + step * 8, p3, cur, x0, x1); step++;
    if (!(h & 8))  { p4 = cur; continue; }
    cur = combine2(gb + step * 8, p4, cur, x0, x1); step++;
    if (!(h & 16)) { p5 = cur; continue; }
    cur = combine2(gb + step * 8, p5, cur, x0, x1); step++;
    if (!(h & 32)) { p6 = cur; continue; }
    cur = combine2(gb + step * 8, p6, cur, x0, x1); step++;
    res = cur;
  }

  v2 v = res;
  { v2 o; o.x = __shfl_xor(v.x, 1); o.y = __shfl_xor(v.y, 1);
    v2 L, R;
    L.x = (lt & 1) ? o.x : v.x; L.y = (lt & 1) ? o.y : v.y;
    R.x = (lt & 1) ? v.x : o.x; R.y = (lt & 1) ? v.y : o.y;
    v = combine2(&tds[(lt >> 1) * 8], L, R, x0, x1); }
  { v2 o; o.x = __shfl_xor(v.x, 2); o.y = __shfl_xor(v.y, 2);
    v2 L, R;
    L.x = (lt & 2) ? o.x : v.x; L.y = (lt & 2) ? o.y : v.y;
    R.x = (lt & 2) ? v.x : o.x; R.y = (lt & 2) ? v.y : o.y;
    v = combine2(&tds[(4 + (lt >> 2)) * 8], L, R, x0, x1); }
  { v2 o; o.x = __shfl_xor(v.x, 4); o.y = __shfl_xor(v.y, 4);
    v2 L, R;
    L.x = (lt & 4) ? o.x : v.x; L.y = (lt & 4) ? o.y : v.y;
    R.x = (lt & 4) ? v.x : o.x; R.y = (lt & 4) ? v.y : o.y;
    v = combine2(&tds[6 * 8], L, R, x0, x1); }

  if (lt == 0) {
    if (cplx) { out0[2 * e] = v.x; out0[2 * e + 1] = v.y; }
    else      { out0[e] = v.x; }
  }
}

__global__ __launch_bounds__(256) void probs_fb_kernel(
    const float* __restrict__ leaf_logits,
    const float* __restrict__ gate_logits,
    float* __restrict__ out_leaf,
    float* __restrict__ out_gate) {
  int i = blockIdx.x * 256 + threadIdx.x;
  if (i < 1024) {
    softmax3_store(leaf_logits[i * 3], leaf_logits[i * 3 + 1], leaf_logits[i * 3 + 2],
                   &out_leaf[i * 3]);
  } else if (i < 1024 + 2046) {
    int j = i - 1024;
    float p[4];
    softmax4(gate_logits + j * 4, p);
    ((float4*)out_gate)[j] = make_float4(p[0], p[1], p[2], p[3]);
  }
}

extern "C" void kernel_launch(void* const* d_in, const int* in_sizes, int n_in,
                              void* d_out, int out_size, void* d_ws, size_t ws_size,
                              hipStream_t stream) {
  const float* x  = (const float*)d_in[0];   // (32768, 2)
  const float* ll = (const float*)d_in[1];   // (1024, 3)
  const float* gl = (const float*)d_in[2];   // (1023, 2, 4)
  float* out0 = (float*)d_out;

  int S = out_size - (3072 + 8184);          // complex chunk: 2*32768 interleaved or 32768 real
  int cplx = (S >= 2 * NBATCH) ? 1 : 0;
  float* out_leaf = out0 + S;
  float* out_gate = out_leaf + 3072;

  if (ws_size >= (size_t)WS_NEED) {
    float* ws_leaf = (float*)d_ws;           // 4096 floats
    float* ws_gate = ws_leaf + 4096;         // 8184 floats
    prep_kernel<<<12, 256, 0, stream>>>(ll, gl, out_leaf, out_gate, ws_leaf, ws_gate);
    tree32p_kernel<<<512, 1024, 0, stream>>>(x, ws_leaf, ws_gate, out0, cplx);
  } else {
    tree_fb_kernel<<<512, 512, 0, stream>>>(x, ll, gl, out0, cplx);
    probs_fb_kernel<<<12, 256, 0, stream>>>(ll, gl, out_leaf, out_gate);
  }
}

// Round 12
// 52.649 us; speedup vs baseline: 1.2549x; 1.0434x over previous
//
#include <hip/hip_runtime.h>
#include <math.h>

#define EPSF     1.1920928955078125e-07f   // float32 eps
#define BYPASSF  0.9999998807907104f       // 1 - eps
#define CLAMPF   1e30f
#define NBATCH   32768

// split constants
#define INV2PI    0.15915494309189535f
#define INV2PI_HI 0.15915493667125701904f  // fp32(1/2pi)
#define INV2PI_LO 6.42063831e-9f           // 1/2pi - hi
#define L2E       1.4426950408889634f
#define L2E_HI    1.44269502162933349609f  // fp32(log2 e)
#define L2E_LO    1.92596299e-8f           // log2e - hi
#define LN2F      0.69314718055994530942f
#define PI_F      3.14159274101257324219f
#define PIO2_F    1.57079637050628662109f

// geometry: 32 subtrees/pair (depth-5 local fold), 2 elements/lane, 32 lanes/pair,
// block=512 (16 pairs), grid=1024 -> 4 blocks/CU x 8 waves = 32 waves/CU (8/SIMD).
// Gates in LDS (33.2KB); leaf table in GLOBAL, transposed [step][subtree] so the
// 32 lanes of a pair read consecutive float4s (coalesced, L1-resident 16KB).
#define SLAB_SRC 248                       // floats per subtree slab in d_ws (31 steps * 8)
#define SLAB_LDS 252                       // floats per slab in LDS
#define GDS_FLOATS (32 * SLAB_LDS + 248)   // + 31 top gates * 8 = 8312 floats = 33,248 B
#define WS_NEED ((4096 + 8184) * 4)        // bytes: leaves + gates

typedef float v2 __attribute__((ext_vector_type(2)));

// inline function, NOT a macro: braced initializer lists in macro args split on commas
__device__ __forceinline__ v2 pkfma(v2 a, v2 b, v2 c) {
  return __builtin_elementwise_fma(a, b, c);
}

struct C2p { v2 r, i; };                   // one complex value for TWO batch elements

__device__ __attribute__((noinline)) float2 slow_sincos(float y) {
  return make_float2(sinf(y), cosf(y));
}

__device__ __forceinline__ void softmax3_store(float a, float b, float c, float* out) {
  float m = fmaxf(a, fmaxf(b, c));
  float e0 = expf(a - m), e1 = expf(b - m), e2 = expf(c - m);
  float s = (e0 + e1) + e2;
  out[0] = e0 / s; out[1] = e1 / s; out[2] = e2 / s;
}

__device__ __forceinline__ void softmax4(const float* __restrict__ in, float* out) {
  float a = in[0], b = in[1], c = in[2], d = in[3];
  float m = fmaxf(fmaxf(a, b), fmaxf(c, d));
  float e0 = expf(a - m), e1 = expf(b - m), e2 = expf(c - m), e3 = expf(d - m);
  float s = ((e0 + e1) + e2) + e3;
  out[0] = e0 / s; out[1] = e1 / s; out[2] = e2 / s; out[3] = e3 / s;
}

// bypass/eps folding (exact: probs sum to 1 -> at most one can exceed 1-eps)
__device__ __forceinline__ void fold_gate(float* p) {
  if (p[3] <= EPSF) p[3] = 0.0f;
  if (p[0] > BYPASSF)      { p[0]=1.f; p[1]=0.f; p[2]=0.f; p[3]=0.f; }
  else if (p[1] > BYPASSF) { p[0]=0.f; p[1]=1.f; p[2]=0.f; p[3]=0.f; }
  else if (p[2] > BYPASSF) { p[0]=0.f; p[1]=0.f; p[2]=1.f; p[3]=0.f; }
}

// ---------------- paired (2-element) combine primitives ----------------
// Per-element arithmetic is bit-identical to the R9/R11 path (verified absmax 0.0).

__device__ __forceinline__ C2p combine2p(const float* __restrict__ g8, C2p L, C2p R,
                                         v2 x0, v2 x1) {
  float4 gl = *(const float4*)(g8);
  float4 gr = *(const float4*)(g8 + 4);
  v2 cL = pkfma((v2)(gl.z), x1, (v2)(gl.y) * x0) + (v2)(gl.x);
  v2 cR = pkfma((v2)(gr.z), x1, (v2)(gr.y) * x0) + (v2)(gr.x);
  v2 linr = pkfma((v2)(gl.w), L.r, cL);
  v2 lini = (v2)(gl.w) * L.i;
  v2 rinr = pkfma((v2)(gr.w), R.r, cR);
  v2 rini = (v2)(gr.w) * R.i;

  // sincos(lini) via revolution-domain Cody-Waite feeding HW v_sin/v_cos
  v2 sy, cy;
  {
    v2 t = lini * (v2)(INV2PI);
    v2 nf; nf.x = rintf(t.x); nf.y = rintf(t.y);
    v2 rv = pkfma(lini, (v2)(INV2PI_HI), -nf);
    rv     = pkfma(lini, (v2)(INV2PI_LO), rv);
    sy.x = __builtin_amdgcn_sinf(rv.x); sy.y = __builtin_amdgcn_sinf(rv.y);
    cy.x = __builtin_amdgcn_cosf(rv.x); cy.y = __builtin_amdgcn_cosf(rv.y);
    if (fabsf(lini.x) > 20000.0f) { float2 sc = slow_sincos(lini.x); sy.x = sc.x; cy.x = sc.y; }
    if (fabsf(lini.y) > 20000.0f) { float2 sc = slow_sincos(lini.y); sy.y = sc.x; cy.y = sc.y; }
  }

  // exp(linr) scaled: covers ldexp_cexpf region and over/underflow
  v2 xe; xe.x = __builtin_amdgcn_fmed3f(linr.x, -200.0f, 200.0f);
         xe.y = __builtin_amdgcn_fmed3f(linr.y, -200.0f, 200.0f);
  v2 t2 = xe * (v2)(L2E);
  v2 nfe; nfe.x = rintf(t2.x); nfe.y = rintf(t2.y);
  v2 f = pkfma(xe, (v2)(L2E_HI), -nfe);
  f     = pkfma(xe, (v2)(L2E_LO), f);
  v2 eh; eh.x = __builtin_amdgcn_exp2f(f.x); eh.y = __builtin_amdgcn_exp2f(f.y);
  int ne0 = (int)nfe.x, ne1 = (int)nfe.y;
  v2 ecr = eh * cy, eci = eh * sy;
  v2 er, ei;
  er.x = __builtin_amdgcn_ldexpf(ecr.x, ne0); er.y = __builtin_amdgcn_ldexpf(ecr.y, ne1);
  ei.x = __builtin_amdgcn_ldexpf(eci.x, ne0); ei.y = __builtin_amdgcn_ldexpf(eci.y, ne1);

  // clog: shared s = mn/mx for log-hypot and atan2
  v2 mx, mn;
  mx.x = fmaxf(fabsf(rinr.x), fabsf(rini.x)); mx.y = fmaxf(fabsf(rinr.y), fabsf(rini.y));
  mn.x = fminf(fabsf(rinr.x), fabsf(rini.x)); mn.y = fminf(fabsf(rinr.y), fabsf(rini.y));
  v2 rc; rc.x = __builtin_amdgcn_rcpf(mx.x); rc.y = __builtin_amdgcn_rcpf(mx.y);
  v2 s = mn * rc;
  s.x = (mx.x == 0.0f) ? 0.0f : s.x;
  s.y = (mx.y == 0.0f) ? 0.0f : s.y;
  v2 z = s * s;
  v2 lga; lga.x = __builtin_amdgcn_logf(z.x + 1.0f); lga.y = __builtin_amdgcn_logf(z.y + 1.0f);
  v2 lgm; lgm.x = __builtin_amdgcn_logf(mx.x);       lgm.y = __builtin_amdgcn_logf(mx.y);
  v2 lr = (v2)(LN2F) * pkfma((v2)(0.5f), lga, lgm);
  v2 u = (v2)(0.00282363896f);
  u = pkfma(u, z, (v2)(-0.0159569028f));
  u = pkfma(u, z, (v2)( 0.0425049886f));
  u = pkfma(u, z, (v2)(-0.0748900920f));
  u = pkfma(u, z, (v2)( 0.1063479334f));
  u = pkfma(u, z, (v2)(-0.1420273631f));
  u = pkfma(u, z, (v2)( 0.1999269574f));
  u = pkfma(u, z, (v2)(-0.3333310186f));
  v2 at = pkfma(s * z, u, s);
  v2 q1 = (v2)(PIO2_F) - at;
  at.x = (fabsf(rini.x) > fabsf(rinr.x)) ? q1.x : at.x;
  at.y = (fabsf(rini.y) > fabsf(rinr.y)) ? q1.y : at.y;
  v2 q2 = (v2)(PI_F) - at;
  at.x = (rinr.x < 0.0f) ? q2.x : at.x;
  at.y = (rinr.y < 0.0f) ? q2.y : at.y;
  v2 li; li.x = copysignf(at.x, rini.x); li.y = copysignf(at.y, rini.y);

  v2 dre = er - lr, dim = ei - li;
  C2p o;
  o.r.x = __builtin_amdgcn_fmed3f(dre.x, -CLAMPF, CLAMPF);
  o.r.y = __builtin_amdgcn_fmed3f(dre.y, -CLAMPF, CLAMPF);
  o.i.x = __builtin_amdgcn_fmed3f(dim.x, -CLAMPF, CLAMPF);
  o.i.y = __builtin_amdgcn_fmed3f(dim.y, -CLAMPF, CLAMPF);
  return o;
}

// level-1 specialization: both children are real leaves (imag exactly 0)
__device__ __forceinline__ C2p combine_l1p(const float* __restrict__ g8, v2 Lr, v2 Rr,
                                           v2 x0, v2 x1) {
  float4 gl = *(const float4*)(g8);
  float4 gr = *(const float4*)(g8 + 4);
  v2 lr_ = pkfma((v2)(gl.w), Lr, pkfma((v2)(gl.z), x1, (v2)(gl.y) * x0) + (v2)(gl.x));
  v2 rr_ = pkfma((v2)(gr.w), Rr, pkfma((v2)(gr.z), x1, (v2)(gr.y) * x0) + (v2)(gr.x));

  v2 xe; xe.x = __builtin_amdgcn_fmed3f(lr_.x, -200.0f, 200.0f);
         xe.y = __builtin_amdgcn_fmed3f(lr_.y, -200.0f, 200.0f);
  v2 t2 = xe * (v2)(L2E);
  v2 nfe; nfe.x = rintf(t2.x); nfe.y = rintf(t2.y);
  v2 f = pkfma(xe, (v2)(L2E_HI), -nfe);
  f     = pkfma(xe, (v2)(L2E_LO), f);
  v2 eh; eh.x = __builtin_amdgcn_exp2f(f.x); eh.y = __builtin_amdgcn_exp2f(f.y);
  v2 er;
  er.x = __builtin_amdgcn_ldexpf(eh.x, (int)nfe.x);
  er.y = __builtin_amdgcn_ldexpf(eh.y, (int)nfe.y);

  v2 lg; lg.x = __builtin_amdgcn_logf(fabsf(rr_.x)); lg.y = __builtin_amdgcn_logf(fabsf(rr_.y));
  v2 d = er - (v2)(LN2F) * lg;
  C2p o;
  o.r.x = __builtin_amdgcn_fmed3f(d.x, -CLAMPF, CLAMPF);  // NaN impossible on this path
  o.r.y = __builtin_amdgcn_fmed3f(d.y, -CLAMPF, CLAMPF);
  o.i.x = (rr_.x < 0.0f) ? -PI_F : 0.0f;
  o.i.y = (rr_.y < 0.0f) ? -PI_F : 0.0f;
  return o;
}

// quartet from the transposed GLOBAL leaf table: entries at stride 32 float4
__device__ __forceinline__ C2p quartetp_g(const float* __restrict__ bp,
                                          const float4* __restrict__ lq,  // stride 32
                                          v2 x0, v2 x1) {
  float4 w0 = lq[0], w1 = lq[32], w2 = lq[64], w3 = lq[96];
  v2 a0 = pkfma((v2)(w0.z), x1, pkfma((v2)(w0.y), x0, (v2)(w0.x)));
  v2 a1 = pkfma((v2)(w1.z), x1, pkfma((v2)(w1.y), x0, (v2)(w1.x)));
  v2 a2 = pkfma((v2)(w2.z), x1, pkfma((v2)(w2.y), x0, (v2)(w2.x)));
  v2 a3 = pkfma((v2)(w3.z), x1, pkfma((v2)(w3.y), x0, (v2)(w3.x)));
  C2p c01 = combine_l1p(bp + 0, a0, a1, x0, x1);
  C2p c23 = combine_l1p(bp + 8, a2, a3, x0, x1);
  return combine2p(bp + 16, c01, c23, x0, x1);
}

// ---------------- prep: softmax + fold + DFS reorder into d_ws, plus probs outputs ----------------
__global__ __launch_bounds__(256) void prep_kernel(
    const float* __restrict__ leaf_logits,
    const float* __restrict__ gate_logits,
    float* __restrict__ out_leaf,   // 1024 x 3 raw
    float* __restrict__ out_gate,   // 2046 x 4 raw
    float* __restrict__ ws_leaf,    // 1024 float4, TRANSPOSED: [local_step][subtree]
    float* __restrict__ ws_gate) {  // 32*248 (DFS levels 1..5) + 31*8 (top, rows 992..1022)
  int i = blockIdx.x * 256 + threadIdx.x;
  if (i < 1024) {
    float p[3];
    softmax3_store(leaf_logits[i * 3], leaf_logits[i * 3 + 1], leaf_logits[i * 3 + 2], p);
    out_leaf[i * 3] = p[0]; out_leaf[i * 3 + 1] = p[1]; out_leaf[i * 3 + 2] = p[2];
    // transposed: leaf i = subtree (i>>5), local pos (i&31) -> entry (i&31)*32 + (i>>5)
    ((float4*)ws_leaf)[(i & 31) * 32 + (i >> 5)] = make_float4(p[0], p[1], p[2], 0.0f);
  } else if (i < 1024 + 2046) {
    int j = i - 1024;                  // gate half-row 0..2045
    int g = j >> 1, half = j & 1;
    float p[4];
    softmax4(gate_logits + j * 4, p);
    ((float4*)out_gate)[j] = make_float4(p[0], p[1], p[2], p[3]);
    fold_gate(p);
    int di;
    if (g < 992) {                     // levels 1..5 -> per-subtree DFS order
      int z  = 1024 - g;
      int k  = __clz(z - 1) - 21;      // 1..5
      int pp = g - (1024 - (2048 >> k));
      int t  = pp >> (5 - k);
      int pl = pp & ((1 << (5 - k)) - 1);
      int L  = ((pl + 1) << k) - 1;
      int step = L - __popc(L) + (k - 1);  // 0..30
      di = t * SLAB_SRC + step * 8;
    } else {
      di = 32 * SLAB_SRC + (g - 992) * 8;  // top 31 gates flat
    }
    ((float4*)(ws_gate + di))[half] = make_float4(p[0], p[1], p[2], p[3]);
  }
}

// ---------------- fast tree: block=512, 4 blocks/CU, gates in LDS, leaves via L1 ----------------
__global__ __launch_bounds__(512, 4) void tree32p_kernel(
    const float* __restrict__ x,
    const float* __restrict__ ws_leaf,
    const float* __restrict__ ws_gate,
    float* __restrict__ out0, int cplx) {

  __shared__ __align__(16) float gds[GDS_FLOATS];             // 33,248 B (gates only)
  const int tid = threadIdx.x;

  // copy gate table ws -> LDS, re-striding slabs 248 -> 252 floats (62 -> 63 float4)
  {
    float4* g4 = (float4*)gds;
    const float4* s4 = (const float4*)ws_gate;
    for (int c = tid; c < 1984; c += 512) {
      int t = c / 62;
      int r = c - t * 62;
      g4[t * 63 + r] = s4[c];
    }
    if (tid < 62) g4[2016 + tid] = s4[1984 + tid];   // top gates (31 x 2 float4)
  }
  __syncthreads();

  const int gtid = blockIdx.x * 512 + tid;
  const int pe = gtid >> 5;          // element pair (elements 2pe, 2pe+1)
  const int lt = tid & 31;           // subtree index
  const float4 xw = ((const float4*)x)[pe];
  v2 x0, x1;
  x0.x = xw.x; x0.y = xw.z;          // x[:,0] of both elements
  x1.x = xw.y; x1.y = xw.w;          // x[:,1] of both elements
  const float* gb  = &gds[lt * SLAB_LDS];
  const float* tds = &gds[32 * SLAB_LDS];
  const float4* lwT = (const float4*)ws_leaf;   // transposed global leaf table

  C2p p4, p5;                        // pending left siblings, levels 4..5
  C2p res; res.r = (v2)(0.0f); res.i = (v2)(0.0f);
  int off = 0;                       // DFS step base * 8 floats

  #pragma unroll 1
  for (int h2 = 0; h2 < 4; ++h2) {   // one octet (8 leaves, two quartets) per iteration
    const float* bp = gb + off;
    const float4* lq = lwT + (8 * h2) * 32 + lt;   // coalesced: lanes hit consecutive f4
    C2p c03 = quartetp_g(bp +  0, lq,       x0, x1);   // leaves 0..3, steps +0,+8,+16
    C2p c47 = quartetp_g(bp + 24, lq + 128, x0, x1);   // leaves 4..7, steps +24,+32,+40
    C2p cur = combine2p(bp + 48, c03, c47, x0, x1);
    // tail merges, levels 4..5 (DFS steps +56, +64)
    if (!(h2 & 1)) { p4 = cur; }
    else {
      cur = combine2p(bp + 56, p4, cur, x0, x1);
      if (!(h2 & 2)) { p5 = cur; }
      else           { res = combine2p(bp + 64, p5, cur, x0, x1); }
    }
    off = (8 * (h2 + 1) - __popc(h2 + 1)) * 8;
  }

  // top 5 levels across the 32 lanes of this pair (gate rows 992..1022 -> tds 0..30)
  C2p v = res;
  { C2p o;
    o.r.x = __shfl_xor(v.r.x, 1); o.r.y = __shfl_xor(v.r.y, 1);
    o.i.x = __shfl_xor(v.i.x, 1); o.i.y = __shfl_xor(v.i.y, 1);
    bool sw = (lt & 1);
    C2p L, R;
    L.r = sw ? o.r : v.r; L.i = sw ? o.i : v.i;
    R.r = sw ? v.r : o.r; R.i = sw ? v.i : o.i;
    v = combine2p(tds + (lt >> 1) * 8, L, R, x0, x1); }          // level 6
  { C2p o;
    o.r.x = __shfl_xor(v.r.x, 2); o.r.y = __shfl_xor(v.r.y, 2);
    o.i.x = __shfl_xor(v.i.x, 2); o.i.y = __shfl_xor(v.i.y, 2);
    bool sw = (lt & 2);
    C2p L, R;
    L.r = sw ? o.r : v.r; L.i = sw ? o.i : v.i;
    R.r = sw ? v.r : o.r; R.i = sw ? v.i : o.i;
    v = combine2p(tds + (16 + (lt >> 2)) * 8, L, R, x0, x1); }   // level 7
  { C2p o;
    o.r.x = __shfl_xor(v.r.x, 4); o.r.y = __shfl_xor(v.r.y, 4);
    o.i.x = __shfl_xor(v.i.x, 4); o.i.y = __shfl_xor(v.i.y, 4);
    bool sw = (lt & 4);
    C2p L, R;
    L.r = sw ? o.r : v.r; L.i = sw ? o.i : v.i;
    R.r = sw ? v.r : o.r; R.i = sw ? v.i : o.i;
    v = combine2p(tds + (24 + (lt >> 3)) * 8, L, R, x0, x1); }   // level 8
  { C2p o;
    o.r.x = __shfl_xor(v.r.x, 8); o.r.y = __shfl_xor(v.r.y, 8);
    o.i.x = __shfl_xor(v.i.x, 8); o.i.y = __shfl_xor(v.i.y, 8);
    bool sw = (lt & 8);
    C2p L, R;
    L.r = sw ? o.r : v.r; L.i = sw ? o.i : v.i;
    R.r = sw ? v.r : o.r; R.i = sw ? v.i : o.i;
    v = combine2p(tds + (28 + (lt >> 4)) * 8, L, R, x0, x1); }   // level 9
  { C2p o;
    o.r.x = __shfl_xor(v.r.x, 16); o.r.y = __shfl_xor(v.r.y, 16);
    o.i.x = __shfl_xor(v.i.x, 16); o.i.y = __shfl_xor(v.i.y, 16);
    bool sw = (lt & 16);
    C2p L, R;
    L.r = sw ? o.r : v.r; L.i = sw ? o.i : v.i;
    R.r = sw ? v.r : o.r; R.i = sw ? v.i : o.i;
    v = combine2p(tds + 30 * 8, L, R, x0, x1); }                 // level 10 root

  if (lt == 0) {
    if (cplx) {
      ((float4*)out0)[pe] = make_float4(v.r.x, v.i.x, v.r.y, v.i.y);
    } else {
      ((float2*)out0)[pe] = make_float2(v.r.x, v.r.y);
    }
  }
}

// ---------------- fallback (single-element path, used only if ws_size is too small) ----------------
#define GSTRIDE  1020
#define LSTRIDE  516

__device__ __forceinline__ v2 combine2(const float* __restrict__ g8, v2 L, v2 R,
                                       float x0, float x1) {
  float4 gl = *(const float4*)(g8);
  float4 gr = *(const float4*)(g8 + 4);
  float cL = fmaf(gl.z, x1, gl.y * x0) + gl.x;
  float cR = fmaf(gr.z, x1, gr.y * x0) + gr.x;
  v2 glw; glw.x = gl.w; glw.y = gl.w;
  v2 grw; grw.x = gr.w; grw.y = gr.w;
  v2 cLv; cLv.x = cL; cLv.y = 0.0f;
  v2 cRv; cRv.x = cR; cRv.y = 0.0f;
  v2 lin = pkfma(glw, L, cLv);
  v2 rin = pkfma(grw, R, cRv);
  float sy, cy;
  {
    float nf = rintf(lin.y * INV2PI);
    float rv = fmaf(lin.y, INV2PI_HI, -nf);
    rv       = fmaf(lin.y, INV2PI_LO, rv);
    sy = __builtin_amdgcn_sinf(rv);
    cy = __builtin_amdgcn_cosf(rv);
    if (fabsf(lin.y) > 20000.0f) { float2 sc = slow_sincos(lin.y); sy = sc.x; cy = sc.y; }
  }
  float xe = fminf(fmaxf(lin.x, -200.0f), 200.0f);
  float nfe = rintf(xe * L2E);
  float f  = fmaf(xe, L2E_HI, -nfe);
  f        = fmaf(xe, L2E_LO, f);
  float eh = __builtin_amdgcn_exp2f(f);
  int ne = (int)nfe;
  float er = __builtin_amdgcn_ldexpf(eh * cy, ne);
  float ei = __builtin_amdgcn_ldexpf(eh * sy, ne);
  float ax = fabsf(rin.x), ay = fabsf(rin.y);
  float mx = fmaxf(ax, ay), mn = fminf(ax, ay);
  float s  = (mx == 0.0f) ? 0.0f : mn * __builtin_amdgcn_rcpf(mx);
  float z  = s * s;
  float lr = LN2F * fmaf(0.5f, __builtin_amdgcn_logf(z + 1.0f), __builtin_amdgcn_logf(mx));
  float u =              0.00282363896f;
  u = fmaf(u, z, -0.0159569028f);
  u = fmaf(u, z,  0.0425049886f);
  u = fmaf(u, z, -0.0748900920f);
  u = fmaf(u, z,  0.1063479334f);
  u = fmaf(u, z, -0.1420273631f);
  u = fmaf(u, z,  0.1999269574f);
  u = fmaf(u, z, -0.3333310186f);
  float at = fmaf(s * z, u, s);
  at = (ay > ax)      ? (PIO2_F - at) : at;
  at = (rin.x < 0.0f) ? (PI_F   - at) : at;
  float li = copysignf(at, rin.y);
  float dx = er - lr, dy = ei - li;
  v2 o;
  o.x = (dx != dx) ? 0.0f : __builtin_amdgcn_fmed3f(dx, -CLAMPF, CLAMPF);
  o.y = (dy != dy) ? 0.0f : __builtin_amdgcn_fmed3f(dy, -CLAMPF, CLAMPF);
  return o;
}

__device__ __forceinline__ v2 combine_l1(const float* __restrict__ g8, float Lr, float Rr,
                                         float x0, float x1) {
  float4 gl = *(const float4*)(g8);
  float4 gr = *(const float4*)(g8 + 4);
  float lr_ = fmaf(gl.w, Lr, fmaf(gl.z, x1, gl.y * x0) + gl.x);
  float rr_ = fmaf(gr.w, Rr, fmaf(gr.z, x1, gr.y * x0) + gr.x);
  float xe = fminf(fmaxf(lr_, -200.0f), 200.0f);
  float nfe = rintf(xe * L2E);
  float f  = fmaf(xe, L2E_HI, -nfe);
  f        = fmaf(xe, L2E_LO, f);
  float eh = __builtin_amdgcn_exp2f(f);
  float er = __builtin_amdgcn_ldexpf(eh, (int)nfe);
  float lr = LN2F * __builtin_amdgcn_logf(fabsf(rr_));
  v2 o;
  o.x = fminf(fmaxf(er - lr, -CLAMPF), CLAMPF);
  o.y = (rr_ < 0.0f) ? -PI_F : 0.0f;
  return o;
}

__device__ __forceinline__ void store_gate_fb(const float* __restrict__ in, float* __restrict__ out) {
  float p[4];
  softmax4(in, p);
  fold_gate(p);
  out[0]=p[0]; out[1]=p[1]; out[2]=p[2]; out[3]=p[3];
}

__global__ __launch_bounds__(512) void tree_fb_kernel(
    const float* __restrict__ x,
    const float* __restrict__ leaf_logits,
    const float* __restrict__ gate_logits,
    float* __restrict__ out0, int cplx) {

  __shared__ __align__(16) float gds[8 * GSTRIDE];
  __shared__ __align__(16) float tds[7 * 8];
  __shared__ __align__(16) float lw[8 * LSTRIDE];
  const int tid = threadIdx.x;

  for (int l = tid; l < 1024; l += 512) {
    float p[3];
    softmax3_store(leaf_logits[l * 3], leaf_logits[l * 3 + 1], leaf_logits[l * 3 + 2], p);
    *(float4*)&lw[(l >> 7) * LSTRIDE + (l & 127) * 4] = make_float4(p[0], p[1], p[2], 0.0f);
  }
  for (int g = tid; g < 1016; g += 512) {
    int z  = 1024 - g;
    int k  = __clz(z - 1) - 21;
    int p  = g - (1024 - (2048 >> k));
    int t  = p >> (7 - k);
    int pl = p & ((1 << (7 - k)) - 1);
    int L  = ((pl + 1) << k) - 1;
    int step = L - __popc(L) + (k - 1);
    float* dst = &gds[t * GSTRIDE + step * 8];
    store_gate_fb(gate_logits + g * 8,     dst);
    store_gate_fb(gate_logits + g * 8 + 4, dst + 4);
  }
  if (tid < 7) {
    int g = 1016 + tid;
    store_gate_fb(gate_logits + g * 8,     &tds[tid * 8]);
    store_gate_fb(gate_logits + g * 8 + 4, &tds[tid * 8 + 4]);
  }
  __syncthreads();

  const int gtid = blockIdx.x * 512 + tid;
  const int e  = gtid >> 3;
  const int lt = tid & 7;
  const float2 xv = ((const float2*)x)[e];
  const float x0 = xv.x, x1 = xv.y;
  const float* gb = &gds[lt * GSTRIDE];
  const float* lb = &lw[lt * LSTRIDE];

  v2 p1, p2, p3, p4, p5, p6;
  v2 res = (v2)(0.0f);
  int step = 0;

  #pragma unroll 2
  for (int h = 0; h < 64; ++h) {
    float4 w0 = *(const float4*)&lb[(2 * h) * 4];
    float4 w1 = *(const float4*)&lb[(2 * h + 1) * 4];
    float a = fmaf(w0.z, x1, fmaf(w0.y, x0, w0.x));
    float b = fmaf(w1.z, x1, fmaf(w1.y, x0, w1.x));
    v2 cur = combine_l1(gb + step * 8, a, b, x0, x1); step++;
    if (!(h & 1))  { p1 = cur; continue; }
    cur = combine2(gb + step * 8, p1, cur, x0, x1); step++;
    if (!(h & 2))  { p2 = cur; continue; }
    cur = combine2(gb + step * 8, p2, cur, x0, x1); step++;
    if (!(h & 4))  { p3 = cur; continue; }
    cur = combine2(gb + step * 8, p3, cur, x0, x1); step++;
    if (!(h & 8))  { p4 = cur; continue; }
    cur = combine2(gb + step * 8, p4, cur, x0, x1); step++;
    if (!(h & 16)) { p5 = cur; continue; }
    cur = combine2(gb + step * 8, p5, cur, x0, x1); step++;
    if (!(h & 32)) { p6 = cur; continue; }
    cur = combine2(gb + step * 8, p6, cur, x0, x1); step++;
    res = cur;
  }

  v2 v = res;
  { v2 o; o.x = __shfl_xor(v.x, 1); o.y = __shfl_xor(v.y, 1);
    v2 L, R;
    L.x = (lt & 1) ? o.x : v.x; L.y = (lt & 1) ? o.y : v.y;
    R.x = (lt & 1) ? v.x : o.x; R.y = (lt & 1) ? v.y : o.y;
    v = combine2(&tds[(lt >> 1) * 8], L, R, x0, x1); }
  { v2 o; o.x = __shfl_xor(v.x, 2); o.y = __shfl_xor(v.y, 2);
    v2 L, R;
    L.x = (lt & 2) ? o.x : v.x; L.y = (lt & 2) ? o.y : v.y;
    R.x = (lt & 2) ? v.x : o.x; R.y = (lt & 2) ? v.y : o.y;
    v = combine2(&tds[(4 + (lt >> 2)) * 8], L, R, x0, x1); }
  { v2 o; o.x = __shfl_xor(v.x, 4); o.y = __shfl_xor(v.y, 4);
    v2 L, R;
    L.x = (lt & 4) ? o.x : v.x; L.y = (lt & 4) ? o.y : v.y;
    R.x = (lt & 4) ? v.x : o.x; R.y = (lt & 4) ? v.y : o.y;
    v = combine2(&tds[6 * 8], L, R, x0, x1); }

  if (lt == 0) {
    if (cplx) { out0[2 * e] = v.x; out0[2 * e + 1] = v.y; }
    else      { out0[e] = v.x; }
  }
}

__global__ __launch_bounds__(256) void probs_fb_kernel(
    const float* __restrict__ leaf_logits,
    const float* __restrict__ gate_logits,
    float* __restrict__ out_leaf,
    float* __restrict__ out_gate) {
  int i = blockIdx.x * 256 + threadIdx.x;
  if (i < 1024) {
    softmax3_store(leaf_logits[i * 3], leaf_logits[i * 3 + 1], leaf_logits[i * 3 + 2],
                   &out_leaf[i * 3]);
  } else if (i < 1024 + 2046) {
    int j = i - 1024;
    float p[4];
    softmax4(gate_logits + j * 4, p);
    ((float4*)out_gate)[j] = make_float4(p[0], p[1], p[2], p[3]);
  }
}

extern "C" void kernel_launch(void* const* d_in, const int* in_sizes, int n_in,
                              void* d_out, int out_size, void* d_ws, size_t ws_size,
                              hipStream_t stream) {
  const float* x  = (const float*)d_in[0];   // (32768, 2)
  const float* ll = (const float*)d_in[1];   // (1024, 3)
  const float* gl = (const float*)d_in[2];   // (1023, 2, 4)
  float* out0 = (float*)d_out;

  int S = out_size - (3072 + 8184);          // complex chunk: 2*32768 interleaved or 32768 real
  int cplx = (S >= 2 * NBATCH) ? 1 : 0;
  float* out_leaf = out0 + S;
  float* out_gate = out_leaf + 3072;

  if (ws_size >= (size_t)WS_NEED) {
    float* ws_leaf = (float*)d_ws;           // 4096 floats (transposed leaf table)
    float* ws_gate = ws_leaf + 4096;         // 8184 floats
    prep_kernel<<<12, 256, 0, stream>>>(ll, gl, out_leaf, out_gate, ws_leaf, ws_gate);
    tree32p_kernel<<<1024, 512, 0, stream>>>(x, ws_leaf, ws_gate, out0, cplx);
  } else {
    tree_fb_kernel<<<512, 512, 0, stream>>>(x, ll, gl, out0, cplx);
    probs_fb_kernel<<<12, 256, 0, stream>>>(ll, gl, out_leaf, out_gate);
  }
}

// Round 13
// 45.975 us; speedup vs baseline: 1.4371x; 1.1452x over previous
//
#include <hip/hip_runtime.h>
#include <math.h>

#define EPSF     1.1920928955078125e-07f   // float32 eps
#define BYPASSF  0.9999998807907104f       // 1 - eps
#define CLAMPF   1e30f
#define NBATCH   32768

// split constants
#define INV2PI    0.15915494309189535f
#define INV2PI_HI 0.15915493667125701904f  // fp32(1/2pi)
#define INV2PI_LO 6.42063831e-9f           // 1/2pi - hi
#define L2E       1.4426950408889634f
#define L2E_HI    1.44269502162933349609f  // fp32(log2 e)
#define L2E_LO    1.92596299e-8f           // log2e - hi
#define LN2F      0.69314718055994530942f
#define PI_F      3.14159274101257324219f
#define PIO2_F    1.57079637050628662109f

// geometry (R9-proven): 16 subtrees/pair (depth-6 local fold), 2 elements/lane,
// 16 lanes/pair, block=1024 (64 pairs), grid=256. SINGLE fused kernel:
// prologue computes softmax+fold+DFS-reorder straight into LDS (no prep launch).
#define SLAB_LDS 508                       // floats per subtree gate slab in LDS
#define GDS_FLOATS (16 * SLAB_LDS + 120)   // + 15 top gates * 8 = 8248 floats = 32,992 B
#define LW_F4_STRIDE 65                    // leaf slab stride in float4 (64 + 1 skew)

typedef float v2 __attribute__((ext_vector_type(2)));

// inline function, NOT a macro: braced initializer lists in macro args split on commas
__device__ __forceinline__ v2 pkfma(v2 a, v2 b, v2 c) {
  return __builtin_elementwise_fma(a, b, c);
}

struct C2p { v2 r, i; };                   // one complex value for TWO batch elements

__device__ __attribute__((noinline)) float2 slow_sincos(float y) {
  return make_float2(sinf(y), cosf(y));
}

__device__ __forceinline__ void softmax3(float a, float b, float c, float* out) {
  float m = fmaxf(a, fmaxf(b, c));
  float e0 = expf(a - m), e1 = expf(b - m), e2 = expf(c - m);
  float s = (e0 + e1) + e2;
  out[0] = e0 / s; out[1] = e1 / s; out[2] = e2 / s;
}

__device__ __forceinline__ void softmax4(const float* __restrict__ in, float* out) {
  float a = in[0], b = in[1], c = in[2], d = in[3];
  float m = fmaxf(fmaxf(a, b), fmaxf(c, d));
  float e0 = expf(a - m), e1 = expf(b - m), e2 = expf(c - m), e3 = expf(d - m);
  float s = ((e0 + e1) + e2) + e3;
  out[0] = e0 / s; out[1] = e1 / s; out[2] = e2 / s; out[3] = e3 / s;
}

// bypass/eps folding (exact: probs sum to 1 -> at most one can exceed 1-eps)
__device__ __forceinline__ void fold_gate(float* p) {
  if (p[3] <= EPSF) p[3] = 0.0f;
  if (p[0] > BYPASSF)      { p[0]=1.f; p[1]=0.f; p[2]=0.f; p[3]=0.f; }
  else if (p[1] > BYPASSF) { p[0]=0.f; p[1]=1.f; p[2]=0.f; p[3]=0.f; }
  else if (p[2] > BYPASSF) { p[0]=0.f; p[1]=0.f; p[2]=1.f; p[3]=0.f; }
}

__device__ __forceinline__ void store_gate(const float* __restrict__ in, float* __restrict__ out) {
  float p[4];
  softmax4(in, p);
  fold_gate(p);
  out[0]=p[0]; out[1]=p[1]; out[2]=p[2]; out[3]=p[3];
}

// ---------------- paired (2-element) combine primitives ----------------
// Per-element arithmetic matches the verified R9 path except blend reassociation
// (3 ops -> 2 fma; sub-ulp change). NaN analysis: inputs clamped-finite; er,ei
// bounded ~1e87 (xe<=200); lr/li finite-or--inf => dre/dim +inf-able, never NaN
// => fmed3 clamp == nan_to_num(posinf=CLAMP)+clip.

__device__ __forceinline__ C2p combine2p(const float* __restrict__ g8, C2p L, C2p R,
                                         v2 x0, v2 x1) {
  float4 gl = *(const float4*)(g8);
  float4 gr = *(const float4*)(g8 + 4);
  v2 cL = pkfma((v2)(gl.z), x1, pkfma((v2)(gl.y), x0, (v2)(gl.x)));
  v2 cR = pkfma((v2)(gr.z), x1, pkfma((v2)(gr.y), x0, (v2)(gr.x)));
  v2 linr = pkfma((v2)(gl.w), L.r, cL);
  v2 lini = (v2)(gl.w) * L.i;
  v2 rinr = pkfma((v2)(gr.w), R.r, cR);
  v2 rini = (v2)(gr.w) * R.i;

  // sincos(lini) via revolution-domain Cody-Waite feeding HW v_sin/v_cos
  v2 sy, cy;
  {
    v2 t = lini * (v2)(INV2PI);
    v2 nf; nf.x = rintf(t.x); nf.y = rintf(t.y);
    v2 rv = pkfma(lini, (v2)(INV2PI_HI), -nf);
    rv     = pkfma(lini, (v2)(INV2PI_LO), rv);
    sy.x = __builtin_amdgcn_sinf(rv.x); sy.y = __builtin_amdgcn_sinf(rv.y);
    cy.x = __builtin_amdgcn_cosf(rv.x); cy.y = __builtin_amdgcn_cosf(rv.y);
    if (fabsf(lini.x) > 20000.0f) { float2 sc = slow_sincos(lini.x); sy.x = sc.x; cy.x = sc.y; }
    if (fabsf(lini.y) > 20000.0f) { float2 sc = slow_sincos(lini.y); sy.y = sc.x; cy.y = sc.y; }
  }

  // exp(linr) scaled: covers ldexp_cexpf region and over/underflow
  v2 xe; xe.x = __builtin_amdgcn_fmed3f(linr.x, -200.0f, 200.0f);
         xe.y = __builtin_amdgcn_fmed3f(linr.y, -200.0f, 200.0f);
  v2 t2 = xe * (v2)(L2E);
  v2 nfe; nfe.x = rintf(t2.x); nfe.y = rintf(t2.y);
  v2 f = pkfma(xe, (v2)(L2E_HI), -nfe);
  f     = pkfma(xe, (v2)(L2E_LO), f);
  v2 eh; eh.x = __builtin_amdgcn_exp2f(f.x); eh.y = __builtin_amdgcn_exp2f(f.y);
  int ne0 = (int)nfe.x, ne1 = (int)nfe.y;
  v2 ecr = eh * cy, eci = eh * sy;
  v2 er, ei;
  er.x = __builtin_amdgcn_ldexpf(ecr.x, ne0); er.y = __builtin_amdgcn_ldexpf(ecr.y, ne1);
  ei.x = __builtin_amdgcn_ldexpf(eci.x, ne0); ei.y = __builtin_amdgcn_ldexpf(eci.y, ne1);

  // clog: shared s = mn/mx for log-hypot and atan2
  v2 mx, mn;
  mx.x = fmaxf(fabsf(rinr.x), fabsf(rini.x)); mx.y = fmaxf(fabsf(rinr.y), fabsf(rini.y));
  mn.x = fminf(fabsf(rinr.x), fabsf(rini.x)); mn.y = fminf(fabsf(rinr.y), fabsf(rini.y));
  v2 rc; rc.x = __builtin_amdgcn_rcpf(mx.x); rc.y = __builtin_amdgcn_rcpf(mx.y);
  v2 s = mn * rc;
  s.x = (mx.x == 0.0f) ? 0.0f : s.x;
  s.y = (mx.y == 0.0f) ? 0.0f : s.y;
  v2 z = s * s;
  v2 lga; lga.x = __builtin_amdgcn_logf(z.x + 1.0f); lga.y = __builtin_amdgcn_logf(z.y + 1.0f);
  v2 lgm; lgm.x = __builtin_amdgcn_logf(mx.x);       lgm.y = __builtin_amdgcn_logf(mx.y);
  v2 lr = (v2)(LN2F) * pkfma((v2)(0.5f), lga, lgm);
  v2 u = (v2)(0.00282363896f);
  u = pkfma(u, z, (v2)(-0.0159569028f));
  u = pkfma(u, z, (v2)( 0.0425049886f));
  u = pkfma(u, z, (v2)(-0.0748900920f));
  u = pkfma(u, z, (v2)( 0.1063479334f));
  u = pkfma(u, z, (v2)(-0.1420273631f));
  u = pkfma(u, z, (v2)( 0.1999269574f));
  u = pkfma(u, z, (v2)(-0.3333310186f));
  v2 at = pkfma(s * z, u, s);
  v2 q1 = (v2)(PIO2_F) - at;
  at.x = (fabsf(rini.x) > fabsf(rinr.x)) ? q1.x : at.x;
  at.y = (fabsf(rini.y) > fabsf(rinr.y)) ? q1.y : at.y;
  v2 q2 = (v2)(PI_F) - at;
  at.x = (rinr.x < 0.0f) ? q2.x : at.x;
  at.y = (rinr.y < 0.0f) ? q2.y : at.y;
  v2 li; li.x = copysignf(at.x, rini.x); li.y = copysignf(at.y, rini.y);

  v2 dre = er - lr, dim = ei - li;
  C2p o;
  o.r.x = __builtin_amdgcn_fmed3f(dre.x, -CLAMPF, CLAMPF);
  o.r.y = __builtin_amdgcn_fmed3f(dre.y, -CLAMPF, CLAMPF);
  o.i.x = __builtin_amdgcn_fmed3f(dim.x, -CLAMPF, CLAMPF);
  o.i.y = __builtin_amdgcn_fmed3f(dim.y, -CLAMPF, CLAMPF);
  return o;
}

// level-1 specialization: both children are real leaves (imag exactly 0)
__device__ __forceinline__ C2p combine_l1p(const float* __restrict__ g8, v2 Lr, v2 Rr,
                                           v2 x0, v2 x1) {
  float4 gl = *(const float4*)(g8);
  float4 gr = *(const float4*)(g8 + 4);
  v2 lr_ = pkfma((v2)(gl.w), Lr, pkfma((v2)(gl.z), x1, pkfma((v2)(gl.y), x0, (v2)(gl.x))));
  v2 rr_ = pkfma((v2)(gr.w), Rr, pkfma((v2)(gr.z), x1, pkfma((v2)(gr.y), x0, (v2)(gr.x))));

  v2 xe; xe.x = __builtin_amdgcn_fmed3f(lr_.x, -200.0f, 200.0f);
         xe.y = __builtin_amdgcn_fmed3f(lr_.y, -200.0f, 200.0f);
  v2 t2 = xe * (v2)(L2E);
  v2 nfe; nfe.x = rintf(t2.x); nfe.y = rintf(t2.y);
  v2 f = pkfma(xe, (v2)(L2E_HI), -nfe);
  f     = pkfma(xe, (v2)(L2E_LO), f);
  v2 eh; eh.x = __builtin_amdgcn_exp2f(f.x); eh.y = __builtin_amdgcn_exp2f(f.y);
  v2 er;
  er.x = __builtin_amdgcn_ldexpf(eh.x, (int)nfe.x);
  er.y = __builtin_amdgcn_ldexpf(eh.y, (int)nfe.y);

  v2 lg; lg.x = __builtin_amdgcn_logf(fabsf(rr_.x)); lg.y = __builtin_amdgcn_logf(fabsf(rr_.y));
  v2 d = er - (v2)(LN2F) * lg;
  C2p o;
  o.r.x = __builtin_amdgcn_fmed3f(d.x, -CLAMPF, CLAMPF);  // NaN impossible on this path
  o.r.y = __builtin_amdgcn_fmed3f(d.y, -CLAMPF, CLAMPF);
  o.i.x = (rr_.x < 0.0f) ? -PI_F : 0.0f;
  o.i.y = (rr_.y < 0.0f) ? -PI_F : 0.0f;
  return o;
}

// quartet: 4 leaves -> depth-2 subtree root (3 combines at static offsets)
__device__ __forceinline__ C2p quartetp(const float* __restrict__ bp, const float4* __restrict__ lq,
                                        v2 x0, v2 x1) {
  float4 w0 = lq[0], w1 = lq[1], w2 = lq[2], w3 = lq[3];
  v2 a0 = pkfma((v2)(w0.z), x1, pkfma((v2)(w0.y), x0, (v2)(w0.x)));
  v2 a1 = pkfma((v2)(w1.z), x1, pkfma((v2)(w1.y), x0, (v2)(w1.x)));
  v2 a2 = pkfma((v2)(w2.z), x1, pkfma((v2)(w2.y), x0, (v2)(w2.x)));
  v2 a3 = pkfma((v2)(w3.z), x1, pkfma((v2)(w3.y), x0, (v2)(w3.x)));
  C2p c01 = combine_l1p(bp + 0, a0, a1, x0, x1);
  C2p c23 = combine_l1p(bp + 8, a2, a3, x0, x1);
  return combine2p(bp + 16, c01, c23, x0, x1);
}

// ---------------- fused kernel: prologue (softmax/fold/reorder -> LDS) + tree ----------------
__global__ __launch_bounds__(1024, 1) void fused_kernel(
    const float* __restrict__ x,
    const float* __restrict__ leaf_logits,
    const float* __restrict__ gate_logits,
    float* __restrict__ out0,
    float* __restrict__ out_leaf,
    float* __restrict__ out_gate, int cplx) {

  __shared__ __align__(16) float gds[GDS_FLOATS];             // 32,992 B
  __shared__ __align__(16) float lwds[16 * LW_F4_STRIDE * 4]; // 16,640 B
  const int tid = threadIdx.x;

  // ---- prologue: gates levels 1..6 (g 0..1007) -> per-subtree DFS order ----
  if (tid < 1008) {
    int g  = tid;
    int z  = 1024 - g;
    int k  = __clz(z - 1) - 21;                  // level 1..6
    int pp = g - (1024 - (2048 >> k));
    int t  = pp >> (6 - k);
    int pl = pp & ((1 << (6 - k)) - 1);
    int L  = ((pl + 1) << k) - 1;
    int step = L - __popc(L) + (k - 1);          // 0..62
    float* dst = &gds[t * SLAB_LDS + step * 8];
    store_gate(gate_logits + g * 8,     dst);
    store_gate(gate_logits + g * 8 + 4, dst + 4);
  } else if (tid < 1008 + 15) {
    int ti = tid - 1008;                         // top gates g = 1008..1022
    int g  = 1008 + ti;
    float* dst = &gds[16 * SLAB_LDS + ti * 8];
    store_gate(gate_logits + g * 8,     dst);
    store_gate(gate_logits + g * 8 + 4, dst + 4);
  }
  // ---- prologue: leaves (1 per thread), skewed slabs stride-65 float4 ----
  {
    int l = tid;
    float p[3];
    softmax3(leaf_logits[l * 3], leaf_logits[l * 3 + 1], leaf_logits[l * 3 + 2], p);
    ((float4*)lwds)[(l >> 6) * LW_F4_STRIDE + (l & 63)] = make_float4(p[0], p[1], p[2], 0.0f);
    // block 0 also writes the probs output chunks (raw softmax, no folding)
    if (blockIdx.x == 0) {
      out_leaf[l * 3] = p[0]; out_leaf[l * 3 + 1] = p[1]; out_leaf[l * 3 + 2] = p[2];
      for (int j = tid; j < 2046; j += 1024) {
        float q[4];
        softmax4(gate_logits + j * 4, q);
        ((float4*)out_gate)[j] = make_float4(q[0], q[1], q[2], q[3]);
      }
    }
  }
  __syncthreads();

  const int gtid = blockIdx.x * 1024 + tid;
  const int pe = gtid >> 4;          // element pair (elements 2pe, 2pe+1)
  const int lt = tid & 15;           // subtree index
  const float4 xw = ((const float4*)x)[pe];
  v2 x0, x1;
  x0.x = xw.x; x0.y = xw.z;          // x[:,0] of both elements
  x1.x = xw.y; x1.y = xw.w;          // x[:,1] of both elements
  const float* gb  = &gds[lt * SLAB_LDS];
  const float* tds = &gds[16 * SLAB_LDS];
  const float4* lwp = (const float4*)lwds + lt * LW_F4_STRIDE;

  C2p p4, p5, p6;                    // pending left siblings, levels 4..6
  C2p res; res.r = (v2)(0.0f); res.i = (v2)(0.0f);
  int off = 0;                       // DFS step base * 8 floats

  #pragma unroll 1
  for (int h2 = 0; h2 < 8; ++h2) {   // one octet (8 leaves, two quartets) per iteration
    const float* bp = gb + off;
    const float4* lq = lwp + 8 * h2;
    C2p c03 = quartetp(bp +  0, lq,     x0, x1);   // leaves 0..3, steps +0,+8,+16
    C2p c47 = quartetp(bp + 24, lq + 4, x0, x1);   // leaves 4..7, steps +24,+32,+40
    C2p cur = combine2p(bp + 48, c03, c47, x0, x1);
    // tail merges, levels 4..6 (DFS steps +56, +64, +72)
    if (!(h2 & 1)) { p4 = cur; }
    else {
      cur = combine2p(bp + 56, p4, cur, x0, x1);
      if (!(h2 & 2)) { p5 = cur; }
      else {
        cur = combine2p(bp + 64, p5, cur, x0, x1);
        if (!(h2 & 4)) { p6 = cur; }
        else           { res = combine2p(bp + 72, p6, cur, x0, x1); }
      }
    }
    off = (8 * (h2 + 1) - __popc(h2 + 1)) * 8;
  }

  // top 4 levels across the 16 lanes of this pair (gate rows 1008..1022 -> tds 0..14)
  C2p v = res;
  { C2p o;
    o.r.x = __shfl_xor(v.r.x, 1); o.r.y = __shfl_xor(v.r.y, 1);
    o.i.x = __shfl_xor(v.i.x, 1); o.i.y = __shfl_xor(v.i.y, 1);
    bool sw = (lt & 1);
    C2p L, R;
    L.r = sw ? o.r : v.r; L.i = sw ? o.i : v.i;
    R.r = sw ? v.r : o.r; R.i = sw ? v.i : o.i;
    v = combine2p(tds + (lt >> 1) * 8, L, R, x0, x1); }          // level 7
  { C2p o;
    o.r.x = __shfl_xor(v.r.x, 2); o.r.y = __shfl_xor(v.r.y, 2);
    o.i.x = __shfl_xor(v.i.x, 2); o.i.y = __shfl_xor(v.i.y, 2);
    bool sw = (lt & 2);
    C2p L, R;
    L.r = sw ? o.r : v.r; L.i = sw ? o.i : v.i;
    R.r = sw ? v.r : o.r; R.i = sw ? v.i : o.i;
    v = combine2p(tds + (8 + (lt >> 2)) * 8, L, R, x0, x1); }    // level 8
  { C2p o;
    o.r.x = __shfl_xor(v.r.x, 4); o.r.y = __shfl_xor(v.r.y, 4);
    o.i.x = __shfl_xor(v.i.x, 4); o.i.y = __shfl_xor(v.i.y, 4);
    bool sw = (lt & 4);
    C2p L, R;
    L.r = sw ? o.r : v.r; L.i = sw ? o.i : v.i;
    R.r = sw ? v.r : o.r; R.i = sw ? v.i : o.i;
    v = combine2p(tds + (12 + (lt >> 3)) * 8, L, R, x0, x1); }   // level 9
  { C2p o;
    o.r.x = __shfl_xor(v.r.x, 8); o.r.y = __shfl_xor(v.r.y, 8);
    o.i.x = __shfl_xor(v.i.x, 8); o.i.y = __shfl_xor(v.i.y, 8);
    bool sw = (lt & 8);
    C2p L, R;
    L.r = sw ? o.r : v.r; L.i = sw ? o.i : v.i;
    R.r = sw ? v.r : o.r; R.i = sw ? v.i : o.i;
    v = combine2p(tds + 14 * 8, L, R, x0, x1); }                 // level 10 root

  if (lt == 0) {
    if (cplx) {
      ((float4*)out0)[pe] = make_float4(v.r.x, v.i.x, v.r.y, v.i.y);
    } else {
      ((float2*)out0)[pe] = make_float2(v.r.x, v.r.y);
    }
  }
}

extern "C" void kernel_launch(void* const* d_in, const int* in_sizes, int n_in,
                              void* d_out, int out_size, void* d_ws, size_t ws_size,
                              hipStream_t stream) {
  const float* x  = (const float*)d_in[0];   // (32768, 2)
  const float* ll = (const float*)d_in[1];   // (1024, 3)
  const float* gl = (const float*)d_in[2];   // (1023, 2, 4)
  float* out0 = (float*)d_out;

  int S = out_size - (3072 + 8184);          // complex chunk: 2*32768 interleaved or 32768 real
  int cplx = (S >= 2 * NBATCH) ? 1 : 0;
  float* out_leaf = out0 + S;
  float* out_gate = out_leaf + 3072;

  fused_kernel<<<256, 1024, 0, stream>>>(x, ll, gl, out0, out_leaf, out_gate, cplx);
}